// Round 4
// baseline (3216.502 us; speedup 1.0000x reference)
//
#include <hip/hip_runtime.h>
#include <math.h>

#define RD 8192   // r (long dim, contiguous in storage)
#define CD 2048   // c (short dim, rows in storage)

typedef _Float16 f16x8 __attribute__((ext_vector_type(8)));
typedef _Float16 f16x4 __attribute__((ext_vector_type(4)));
typedef float    f32x4 __attribute__((ext_vector_type(4)));

#define GLOBAL_AS __attribute__((address_space(1)))
#define LDS_AS    __attribute__((address_space(3)))

// ============================================================================
// f16 MFMA GEMM (NT): C[i][j] = sum_k A[i*K+k] * B[j*K+k], fp32 accumulate.
// R4: counted-vmcnt pipeline (T4). 4 LDS buffers, prefetch depth 2, ONE raw
// s_barrier per K-step with s_waitcnt vmcnt(8) — prefetch loads stay in
// flight across the barrier (no vmcnt(0) drain). Overwrite safety: STAGE(t+2)
// reuses the slot of tile t-2, whose reads finished before the iter-(t-1)
// barrier. Last two iterations peeled with vmcnt(4)/vmcnt(0).
// Requires kchunk/32 >= 2 (all call sites have >= 32).
// mode A (Cp != 0): split-K partial sums via atomicAdd into zeroed fp32 C.
// mode B (Cp == 0): Of16[i][j] = f16( sgn*acc + beta*Dg[ij] + gamma*Eg[ij] )
// ============================================================================
__global__ __launch_bounds__(256) void gemm_nt_f16(
    const _Float16* __restrict__ A, const _Float16* __restrict__ B,
    float* __restrict__ Cp, _Float16* __restrict__ Of16,
    const float* __restrict__ Dg, const _Float16* __restrict__ Eg,
    int M, int N, int K, int ksplit, float beta, float gamma, float sgn)
{
  __shared__ __align__(1024) _Float16 As[4][128 * 32];
  __shared__ __align__(1024) _Float16 Bs[4][128 * 32];
  const int tid = threadIdx.x;
  const int wave = tid >> 6, lane = tid & 63;
  const int wy = wave >> 1, wx = wave & 1;
  const int bi = blockIdx.y * 128, bj = blockIdx.x * 128;
  const int kchunk = K / ksplit;
  const long k0 = (long)blockIdx.z * kchunk;

  f32x4 acc[4][4];
#pragma unroll
  for (int i = 0; i < 4; ++i)
#pragma unroll
    for (int j = 0; j < 4; ++j) acc[i][j] = (f32x4){0.f, 0.f, 0.f, 0.f};

  const int srow = wave * 16 + (lane >> 2);
  const int skof = (lane & 3) * 8;
  const _Float16* aA = A + (long)(bi + srow) * K + k0 + skof;
  const _Float16* aB = B + (long)(bj + srow) * K + k0 + skof;
  const int ldso = wave * 16 * 32;

  // 4 global_load_lds per wave per STAGE (2 for A, 2 for B)
#define STAGE(buf, kt)                                                         \
  {                                                                            \
    _Float16* lA = &As[buf][ldso];                                             \
    _Float16* lB = &Bs[buf][ldso];                                             \
    _Pragma("unroll")                                                          \
    for (int q = 0; q < 2; ++q) {                                              \
      __builtin_amdgcn_global_load_lds(                                        \
          (const GLOBAL_AS unsigned int*)(aA + (long)q * 64 * K + (kt)),       \
          (LDS_AS unsigned int*)(lA + q * 64 * 32), 16, 0, 0);                 \
      __builtin_amdgcn_global_load_lds(                                        \
          (const GLOBAL_AS unsigned int*)(aB + (long)q * 64 * K + (kt)),       \
          (LDS_AS unsigned int*)(lB + q * 64 * 32), 16, 0, 0);                 \
    }                                                                          \
  }

  const int fr = lane & 15;
  const int fk = (lane >> 4) * 8;

#define COMPUTE(slot)                                                          \
  {                                                                            \
    f16x8 af[4], bf[4];                                                        \
    _Pragma("unroll")                                                          \
    for (int t = 0; t < 4; ++t) {                                              \
      af[t] = *(const f16x8*)(&As[slot][(wy * 64 + t * 16 + fr) * 32 + fk]);   \
      bf[t] = *(const f16x8*)(&Bs[slot][(wx * 64 + t * 16 + fr) * 32 + fk]);   \
    }                                                                          \
    _Pragma("unroll")                                                          \
    for (int mt = 0; mt < 4; ++mt)                                             \
      _Pragma("unroll")                                                        \
      for (int nt = 0; nt < 4; ++nt)                                           \
        acc[mt][nt] = __builtin_amdgcn_mfma_f32_16x16x32_f16(                  \
            af[mt], bf[nt], acc[mt][nt], 0, 0, 0);                             \
  }

  const int nt_ = kchunk >> 5;        // number of 32-deep K tiles (>= 2)
  STAGE(0, 0);
  STAGE(1, 32);
  for (int i = 0; i + 2 < nt_; ++i) {
    STAGE((i + 2) & 3, (i + 2) * 32);                 // keep pipe 2 deep
    asm volatile("s_waitcnt vmcnt(8)" ::: "memory");  // tile i resident
    __builtin_amdgcn_s_barrier();
    COMPUTE(i & 3);
  }
  // peeled: tile nt_-2 (one tile still in flight)
  asm volatile("s_waitcnt vmcnt(4)" ::: "memory");
  __builtin_amdgcn_s_barrier();
  COMPUTE((nt_ - 2) & 3);
  // peeled: tile nt_-1 (drain)
  asm volatile("s_waitcnt vmcnt(0)" ::: "memory");
  __builtin_amdgcn_s_barrier();
  COMPUTE((nt_ - 1) & 3);
#undef STAGE
#undef COMPUTE

  const int quad = lane >> 4, fc = lane & 15;
  if (Cp) {
#pragma unroll
    for (int mt = 0; mt < 4; ++mt)
#pragma unroll
      for (int nt = 0; nt < 4; ++nt) {
        const int col = bj + wx * 64 + nt * 16 + fc;
#pragma unroll
        for (int reg = 0; reg < 4; ++reg) {
          const int row = bi + wy * 64 + mt * 16 + quad * 4 + reg;
          atomicAdd(&Cp[(long)row * N + col], acc[mt][nt][reg]);
        }
      }
  } else {
#pragma unroll
    for (int mt = 0; mt < 4; ++mt)
#pragma unroll
      for (int nt = 0; nt < 4; ++nt) {
        const int col = bj + wx * 64 + nt * 16 + fc;
#pragma unroll
        for (int reg = 0; reg < 4; ++reg) {
          const int row = bi + wy * 64 + mt * 16 + quad * 4 + reg;
          const long off = (long)row * N + col;
          float v = sgn * acc[mt][nt][reg];
          if (Dg) v += beta * Dg[off];
          if (Eg) v += gamma * (float)Eg[off];
          Of16[off] = (_Float16)v;
        }
      }
  }
}

// ============================================================================
// sym_combine: out[i][j] = scale * sum_z (Cp[z][i][j] + Cp[z][j][i]), n x n fp32.
// ============================================================================
__global__ __launch_bounds__(256) void sym_combine(
    const float* __restrict__ Cp, float* __restrict__ out, int n, int nsplit, float scale)
{
  __shared__ float Ts[64][68];
  const int tid = threadIdx.x;
  const int tx = tid & 15, ty = tid >> 4;
  const int bi = blockIdx.y * 64, bj = blockIdx.x * 64;
  float acc[4][4];
#pragma unroll
  for (int i = 0; i < 4; ++i)
#pragma unroll
    for (int j = 0; j < 4; ++j) acc[i][j] = 0.f;

  for (int s = 0; s < nsplit; ++s) {
    const float* C = Cp + (long)s * n * n;
#pragma unroll
    for (int i = 0; i < 4; ++i) {
      float4 v = *(const float4*)(C + (long)(bi + ty * 4 + i) * n + bj + tx * 4);
      acc[i][0] += v.x; acc[i][1] += v.y; acc[i][2] += v.z; acc[i][3] += v.w;
    }
    __syncthreads();
#pragma unroll
    for (int i = 0; i < 4; ++i) {
      float4 w = *(const float4*)(C + (long)(bj + ty * 4 + i) * n + bi + tx * 4);
      *(float4*)&Ts[ty * 4 + i][tx * 4] = w;
    }
    __syncthreads();
#pragma unroll
    for (int i = 0; i < 4; ++i)
#pragma unroll
      for (int j = 0; j < 4; ++j) acc[i][j] += Ts[tx * 4 + j][ty * 4 + i];
  }
#pragma unroll
  for (int i = 0; i < 4; ++i) {
    float4 v; v.x = scale * acc[i][0]; v.y = scale * acc[i][1]; v.z = scale * acc[i][2]; v.w = scale * acc[i][3];
    *(float4*)(out + (long)(bi + ty * 4 + i) * n + bj + tx * 4) = v;
  }
}

// ============================================================================
// Casts / transposes.
// ============================================================================
__global__ __launch_bounds__(256) void cast_f16(const float* __restrict__ s, _Float16* __restrict__ d)
{
  const long i = ((long)blockIdx.x * 256 + threadIdx.x) * 4;
  float4 v = *(const float4*)(s + i);
  f16x4 o; o[0] = (_Float16)v.x; o[1] = (_Float16)v.y; o[2] = (_Float16)v.z; o[3] = (_Float16)v.w;
  *(f16x4*)(d + i) = o;
}

__global__ __launch_bounds__(256) void cast_f32(const _Float16* __restrict__ s, float* __restrict__ d)
{
  const long i = ((long)blockIdx.x * 256 + threadIdx.x) * 8;
  f16x8 v = *(const f16x8*)(s + i);
  float4 a, b;
  a.x = (float)v[0]; a.y = (float)v[1]; a.z = (float)v[2]; a.w = (float)v[3];
  b.x = (float)v[4]; b.y = (float)v[5]; b.z = (float)v[6]; b.w = (float)v[7];
  *(float4*)(d + i) = a;
  *(float4*)(d + i + 4) = b;
}

__global__ __launch_bounds__(256) void transpose_cast_f16(
    const float* __restrict__ src, _Float16* __restrict__ dst)
{
  __shared__ float T[64][65];
  const int tid = threadIdx.x, tx = tid & 15, ty = tid >> 4;
  const int r0 = blockIdx.x * 64, c0 = blockIdx.y * 64;
#pragma unroll
  for (int i = 0; i < 4; ++i) {
    float4 v = *(const float4*)(src + (long)(c0 + ty * 4 + i) * RD + r0 + tx * 4);
    T[ty * 4 + i][tx * 4 + 0] = v.x; T[ty * 4 + i][tx * 4 + 1] = v.y;
    T[ty * 4 + i][tx * 4 + 2] = v.z; T[ty * 4 + i][tx * 4 + 3] = v.w;
  }
  __syncthreads();
#pragma unroll
  for (int i = 0; i < 4; ++i) {
    f16x4 o;
#pragma unroll
    for (int j = 0; j < 4; ++j) o[j] = (_Float16)T[tx * 4 + j][ty * 4 + i];
    *(f16x4*)(dst + (long)(r0 + ty * 4 + i) * CD + c0 + tx * 4) = o;
  }
}

// f16 (CD x RD) -> f16 (RD x CD) transpose, 64x64 tiles
__global__ __launch_bounds__(256) void transpose_f16(
    const _Float16* __restrict__ src, _Float16* __restrict__ dst)
{
  __shared__ _Float16 T[64][72];
  const int tid = threadIdx.x;
  const int r0 = blockIdx.y * 64;   // src row (CD)
  const int c0 = blockIdx.x * 64;   // src col (RD)
  const int sr = tid >> 2, sc = (tid & 3) * 16;
  {
    f16x8 a = *(const f16x8*)(src + (long)(r0 + sr) * RD + c0 + sc);
    f16x8 b = *(const f16x8*)(src + (long)(r0 + sr) * RD + c0 + sc + 8);
    *(f16x8*)&T[sr][sc] = a;
    *(f16x8*)&T[sr][sc + 8] = b;
  }
  __syncthreads();
  {
    f16x8 a, b;
#pragma unroll
    for (int q = 0; q < 8; ++q) { a[q] = T[sc + q][sr]; b[q] = T[sc + 8 + q][sr]; }
    *(f16x8*)(dst + (long)(c0 + sr) * CD + r0 + sc) = a;
    *(f16x8*)(dst + (long)(c0 + sr) * CD + r0 + sc + 8) = b;
  }
}

// ============================================================================
// Diag-of-Gram reductions on f16 G.
// ============================================================================
__global__ __launch_bounds__(256) void row_sumsq(const _Float16* __restrict__ G, float* __restrict__ out, float inv)
{
  __shared__ float red[256];
  const int tid = threadIdx.x;
  const _Float16* row = G + (long)blockIdx.x * RD;
  float s = 0.f;
  for (int c = tid * 8; c < RD; c += 2048) {
    f16x8 v = *(const f16x8*)(row + c);
#pragma unroll
    for (int u = 0; u < 8; ++u) { float f = (float)v[u]; s += f * f; }
  }
  red[tid] = s; __syncthreads();
  for (int off = 128; off > 0; off >>= 1) { if (tid < off) red[tid] += red[tid + off]; __syncthreads(); }
  if (tid == 0) out[blockIdx.x] = red[0] * inv;
}

__global__ __launch_bounds__(256) void col_sumsq(const _Float16* __restrict__ G, float* __restrict__ out)
{
  const int rr = blockIdx.x * 256 + threadIdx.x;
  const int cc0 = blockIdx.y * 256;
  float s = 0.f;
  for (int i = 0; i < 256; ++i) {
    float v = (float)G[(long)(cc0 + i) * RD + rr];
    s += v * v;
  }
  atomicAdd(&out[rr], s * (1.f / (float)CD));
}

// ============================================================================
// 2-layer LSTM single step + linear head.
// ============================================================================
__device__ __forceinline__ float sigm_(float x) { return 1.f / (1.f + __expf(-x)); }
__device__ __forceinline__ float tanh_(float x) { float e = __expf(2.f * x); return 1.f - 2.f / (e + 1.f); }

__global__ __launch_bounds__(256) void lstm_head(
    const float* __restrict__ diag, int B,
    const float* __restrict__ h0, const float* __restrict__ c0,
    const float* __restrict__ Wih0, const float* __restrict__ Whh0,
    const float* __restrict__ bih0, const float* __restrict__ bhh0,
    const float* __restrict__ Wih1, const float* __restrict__ Whh1,
    const float* __restrict__ bih1, const float* __restrict__ bhh1,
    const float* __restrict__ HW, const float* __restrict__ Hb,
    float* __restrict__ pre, float* __restrict__ sum_out)
{
  __shared__ float w0[80], wh0[1600], b0[80], wi1[1600], wh1[1600], b1[80], hw[20];
  __shared__ float red[256];
  const int tid = threadIdx.x;
  for (int i = tid; i < 80; i += 256) { w0[i] = Wih0[i]; b0[i] = bih0[i] + bhh0[i]; b1[i] = bih1[i] + bhh1[i]; }
  for (int i = tid; i < 1600; i += 256) { wh0[i] = Whh0[i]; wi1[i] = Wih1[i]; wh1[i] = Whh1[i]; }
  if (tid < 20) hw[tid] = HW[tid];
  __syncthreads();

  const int b = blockIdx.x * 256 + tid;
  const float d = diag[b];
  float x = logf(fabsf(d)) * 0.1f;
  x = fminf(fmaxf(x, -1.f), 1.f);

  const float* h0p = h0 + (long)b * 20;
  const float* c0p = c0 + (long)b * 20;
  const float* h1p = h0 + (long)B * 20 + (long)b * 20;
  const float* c1p = c0 + (long)B * 20 + (long)b * 20;

  float h0r[20], hA[20];
#pragma unroll
  for (int m = 0; m < 20; ++m) h0r[m] = h0p[m];
#pragma unroll
  for (int h = 0; h < 20; ++h) {
    float gi = w0[h] * x + b0[h];
    float gf = w0[20 + h] * x + b0[20 + h];
    float gg = w0[40 + h] * x + b0[40 + h];
    float go = w0[60 + h] * x + b0[60 + h];
#pragma unroll
    for (int m = 0; m < 20; ++m) {
      const float hm = h0r[m];
      gi += wh0[h * 20 + m] * hm;
      gf += wh0[(20 + h) * 20 + m] * hm;
      gg += wh0[(40 + h) * 20 + m] * hm;
      go += wh0[(60 + h) * 20 + m] * hm;
    }
    const float cc = sigm_(gf) * c0p[h] + sigm_(gi) * tanh_(gg);
    hA[h] = sigm_(go) * tanh_(cc);
  }
  float h1r[20];
#pragma unroll
  for (int m = 0; m < 20; ++m) h1r[m] = h1p[m];
  float pr = 0.f;
#pragma unroll
  for (int h = 0; h < 20; ++h) {
    float gi = b1[h], gf = b1[20 + h], gg = b1[40 + h], go = b1[60 + h];
#pragma unroll
    for (int m = 0; m < 20; ++m) {
      const float am = hA[m], hm = h1r[m];
      gi += wi1[h * 20 + m] * am + wh1[h * 20 + m] * hm;
      gf += wi1[(20 + h) * 20 + m] * am + wh1[(20 + h) * 20 + m] * hm;
      gg += wi1[(40 + h) * 20 + m] * am + wh1[(40 + h) * 20 + m] * hm;
      go += wi1[(60 + h) * 20 + m] * am + wh1[(60 + h) * 20 + m] * hm;
    }
    const float cc = sigm_(gf) * c1p[h] + sigm_(gi) * tanh_(gg);
    pr += sigm_(go) * tanh_(cc) * hw[h];
  }
  pr = (pr + Hb[0]) * 0.1f;
  pre[b] = pr;

  red[tid] = pr; __syncthreads();
  for (int off = 128; off > 0; off >>= 1) { if (tid < off) red[tid] += red[tid + off]; __syncthreads(); }
  if (tid == 0) atomicAdd(sum_out, red[0]);
}

// ============================================================================
// Pt[cc][rr] = Rv(cc) * Gt[cc][rr] * Lv(rr), in place on f16.
// ============================================================================
__global__ __launch_bounds__(256) void scale_P(
    _Float16* __restrict__ G, const float* __restrict__ lpre, const float* __restrict__ rpre,
    const float* __restrict__ Lbef, const float* __restrict__ Rbef, const float* __restrict__ sums)
{
  const long id4 = ((long)blockIdx.x * 256 + threadIdx.x) * 4;
  const int cc = (int)(id4 >> 13);
  const int rr = (int)(id4 & (RD - 1));
  const float meanl = sums[0] * (1.f / (float)RD);
  const float meanr = sums[1] * (1.f / (float)CD);
  const float rv = fmaxf(rpre[cc] - meanr + 1.f, Rbef[cc]);
  f16x4 g = *(f16x4*)(G + id4);
  float4 lp = *(const float4*)(lpre + rr);
  float4 lb = *(const float4*)(Lbef + rr);
  g[0] = (_Float16)((float)g[0] * rv * fmaxf(lp.x - meanl + 1.f, lb.x));
  g[1] = (_Float16)((float)g[1] * rv * fmaxf(lp.y - meanl + 1.f, lb.y));
  g[2] = (_Float16)((float)g[2] * rv * fmaxf(lp.z - meanl + 1.f, lb.z));
  g[3] = (_Float16)((float)g[3] * rv * fmaxf(lp.w - meanl + 1.f, lb.w));
  *(f16x4*)(G + id4) = g;
}

// ============================================================================
// potrf_block_dev: factor the 64x64 diag block d of S, optionally first
// applying step-kprev's trailing update to it (lookahead fusion).
// Produces: W diag block d  = inv(L_dd)   (full 64x64 incl. upper zeros)
//           KinvA[d]        = inv(L_dd)^T inv(L_dd)
//
// Parallel algorithm (verified R3): deferred-scale right-looking Cholesky
// (64 barriers, rank-1 updates over 256 threads) + inv(L) by in-LDS block
// doubling (4 parallel 16x16 serial inverses, then 16->32, 32->64 matmuls).
// ============================================================================
__device__ __forceinline__ void potrf_block_dev(
    float* __restrict__ S, float* __restrict__ W, float* __restrict__ KinvA,
    int d, int kprev, float (*Ls)[68], float (*Ws)[68], float (*Ts)[68])
{
  const int tid = threadIdx.x;
  const int tx = tid & 15, ty = tid >> 4;
  const long dofs = (long)d * 64;

  for (int t = tid; t < 4096; t += 256) {
    int r = t >> 6, c = t & 63;
    Ls[r][c] = S[(dofs + r) * CD + dofs + c];
  }

  if (kprev >= 0) {
    const float* Kp = KinvA + (long)kprev * 4096;
    const long ko = (long)kprev * 64;
    for (int t = tid; t < 4096; t += 256) {
      int r = t >> 6, c = t & 63;
      Ts[r][c] = S[(dofs + r) * CD + ko + c];   // P = S(d, kprev), pre-step
      Ws[r][c] = Kp[t];                          // Kinv (symmetric)
    }
    __syncthreads();
    float u[4][4];
#pragma unroll
    for (int i = 0; i < 4; ++i)
#pragma unroll
      for (int j = 0; j < 4; ++j) u[i][j] = 0.f;
    for (int m = 0; m < 64; ++m) {
      float a[4], k2[4];
#pragma unroll
      for (int q = 0; q < 4; ++q) { a[q] = Ts[ty * 4 + q][m]; k2[q] = Ws[m][tx * 4 + q]; }
#pragma unroll
      for (int i = 0; i < 4; ++i)
#pragma unroll
        for (int j = 0; j < 4; ++j) u[i][j] += a[i] * k2[j];
    }
    __syncthreads();
#pragma unroll
    for (int i = 0; i < 4; ++i)
#pragma unroll
      for (int j = 0; j < 4; ++j) Ws[ty * 4 + i][tx * 4 + j] = u[i][j];   // U = P*Kinv
    __syncthreads();
    // Ls -= U * P^T   (result stays symmetric)
    float acc[4][4];
#pragma unroll
    for (int i = 0; i < 4; ++i)
#pragma unroll
      for (int j = 0; j < 4; ++j) acc[i][j] = 0.f;
    for (int m = 0; m < 64; ++m) {
      float a[4], b2[4];
#pragma unroll
      for (int q = 0; q < 4; ++q) { a[q] = Ws[ty * 4 + q][m]; b2[q] = Ts[tx * 4 + q][m]; }
#pragma unroll
      for (int i = 0; i < 4; ++i)
#pragma unroll
        for (int j = 0; j < 4; ++j) acc[i][j] += a[i] * b2[j];
    }
#pragma unroll
    for (int i = 0; i < 4; ++i)
#pragma unroll
      for (int j = 0; j < 4; ++j) Ls[ty * 4 + i][tx * 4 + j] -= acc[i][j];
  }

  // --- 1. deferred-scale right-looking Cholesky (lower triangle of Ls) -----
  for (int j = 0; j < 64; ++j) {
    __syncthreads();                                 // step j-1 writes visible
    const float invd = 1.f / Ls[j][j];
    for (int i = j + 1 + ty; i < 64; i += 16) {
      const float vi = Ls[i][j] * invd;
      for (int c = j + 1 + tx; c <= i; c += 16)
        Ls[i][c] -= vi * Ls[c][j];
    }
  }
  __syncthreads();
  if (tid < 64) Ts[0][tid] = 1.f / sqrtf(Ls[tid][tid]);   // rsqrt of pivots
  __syncthreads();
  for (int t = tid; t < 4096; t += 256) {            // scale: L[i][j]=Ls[i][j]*rs[j]
    int r = t >> 6, c = t & 63;
    if (c <= r) Ls[r][c] *= Ts[0][c];
  }
  // zero Ws (upper zeros needed downstream)
  for (int t = tid; t < 4096; t += 256) { int r = t >> 6, c = t & 63; Ws[r][c] = 0.f; }
  __syncthreads();

  // --- 2a. four parallel 16x16 inverses (wave w -> diag block w) -----------
  {
    const int w = tid >> 6, l = tid & 63;
    if (l < 16) {
      const int o = w * 16, c = l;
      float wr[16];
#pragma unroll
      for (int m = 0; m < 16; ++m) {
        float s = 0.f;
#pragma unroll
        for (int k = 0; k < m; ++k) s += Ls[o + m][o + k] * wr[k];
        const float rli = 1.f / Ls[o + m][o + m];
        wr[m] = (m == c) ? rli : -s * rli;
      }
#pragma unroll
      for (int m = 0; m < 16; ++m) Ws[o + m][o + c] = (m < c) ? 0.f : wr[m];
    }
  }
  __syncthreads();

  // --- 2b. doubling 16->32: pairs p=0,1 at b0=32p:
  //     T = L21*W11 (16x16), W21 = -W22*T
  {
    for (int e = tid; e < 512; e += 256) {
      const int p = e >> 8, m = (e >> 4) & 15, c = e & 15, b0 = p * 32;
      float s = 0.f;
#pragma unroll
      for (int k = 0; k < 16; ++k) s += Ls[b0 + 16 + m][b0 + k] * Ws[b0 + k][b0 + c];
      Ts[p * 16 + m][c] = s;
    }
    __syncthreads();
    for (int e = tid; e < 512; e += 256) {
      const int p = e >> 8, m = (e >> 4) & 15, c = e & 15, b0 = p * 32;
      float s = 0.f;
#pragma unroll
      for (int k = 0; k < 16; ++k) s += Ws[b0 + 16 + m][b0 + 16 + k] * Ts[p * 16 + k][c];
      Ws[b0 + 16 + m][b0 + c] = -s;
    }
  }
  __syncthreads();

  // --- 2c. doubling 32->64: T2 = L21'*W11' (32x32), W21' = -W22'*T2 --------
  {
    for (int q = 0; q < 4; ++q) {
      const int e = tid + 256 * q, m = e >> 5, c = e & 31;
      float s = 0.f;
#pragma unroll
      for (int k = 0; k < 32; ++k) s += Ls[32 + m][k] * Ws[k][c];
      Ts[m][c] = s;
    }
    __syncthreads();
    for (int q = 0; q < 4; ++q) {
      const int e = tid + 256 * q, m = e >> 5, c = e & 31;
      float s = 0.f;
#pragma unroll
      for (int k = 0; k < 32; ++k) s += Ws[32 + m][32 + k] * Ts[k][c];
      Ws[32 + m][c] = -s;
    }
  }
  __syncthreads();

  // store W diag block (row-major, incl. upper zeros)
  for (int t = tid; t < 4096; t += 256) {
    int r = t >> 6, c = t & 63;
    W[(dofs + r) * 2048 + dofs + c] = Ws[r][c];
  }
  // KinvA[d] = W^T W : Kinv[a][b] = sum_m Ws[m][a] * Ws[m][b]
  {
    float acc[4][4];
#pragma unroll
    for (int i = 0; i < 4; ++i)
#pragma unroll
      for (int j = 0; j < 4; ++j) acc[i][j] = 0.f;
    for (int m = 0; m < 64; ++m) {
      float a[4], b2[4];
#pragma unroll
      for (int q = 0; q < 4; ++q) { a[q] = Ws[m][ty * 4 + q]; b2[q] = Ws[m][tx * 4 + q]; }
#pragma unroll
      for (int i = 0; i < 4; ++i)
#pragma unroll
        for (int j = 0; j < 4; ++j) acc[i][j] += a[i] * b2[j];
    }
    float* Kd = KinvA + (long)d * 4096;
#pragma unroll
    for (int i = 0; i < 4; ++i)
#pragma unroll
      for (int j = 0; j < 4; ++j)
        Kd[(ty * 4 + i) * 64 + tx * 4 + j] = acc[i][j];
  }
}

__global__ __launch_bounds__(256) void potrf_seed(
    float* __restrict__ S, float* __restrict__ W, float* __restrict__ KinvA)
{
  __shared__ float Ls[64][68];
  __shared__ float Ws[64][68];
  __shared__ float Ts[64][68];
  potrf_block_dev(S, W, KinvA, 0, -1, Ls, Ws, Ts);
}

// ============================================================================
// ptstep_f: fused panel + trailing update + lookahead potrf for step kb.
// by==0 (panel): L(ib,kb) = Spre(ib,kb)*Ws(kb)^T, stored TRANSPOSED in the
//   upper mirror S[kb-rows, ib-cols]. Pre-step reads only.
// 1<=by<=nrem (trail): S(ib,jb) -= Spre(ib,kb)*Kinv[kb]*Spre(jb,kb)^T.
//   Skips (kb+1,kb+1) — the lookahead block handles it.
// by==nrem+1, bx==0 (lookahead): self-update + factor diag kb+1, emit
//   W diag kb+1 and Kinv[kb+1] for the next dispatch.
// All roles read only column-kb pre-values + disjoint outputs -> race-free.
// ============================================================================
__global__ __launch_bounds__(256) void ptstep_f(
    float* __restrict__ S, float* __restrict__ W, float* __restrict__ KinvA, int kb)
{
  __shared__ float As[64][68];
  __shared__ float Bs[64][68];
  __shared__ float Ts[64][68];
  const int tid = threadIdx.x, tx = tid & 15, ty = tid >> 4;
  const long ko = (long)kb * 64;
  const int nrem = 31 - kb;

  if (blockIdx.y == (unsigned)(nrem + 1)) {
    if (blockIdx.x != 0) return;
    potrf_block_dev(S, W, KinvA, kb + 1, kb, As, Bs, Ts);
    return;
  }

  if (blockIdx.y == 0) {
    const int ib = kb + 1 + blockIdx.x;
    const long ro = (long)ib * 64;
    for (int t = tid; t < 4096; t += 256) {
      int r = t >> 6, c = t & 63;
      As[r][c] = S[(ro + r) * CD + ko + c];
      Bs[r][c] = W[(ko + r) * 2048 + ko + c];   // Ws = inv(Lkk)
    }
    __syncthreads();
    float acc[4][4];
#pragma unroll
    for (int i = 0; i < 4; ++i)
#pragma unroll
      for (int j = 0; j < 4; ++j) acc[i][j] = 0.f;
    for (int m = 0; m < 64; ++m) {
      float a[4], w[4];
#pragma unroll
      for (int q = 0; q < 4; ++q) { a[q] = As[ty * 4 + q][m]; w[q] = Bs[tx * 4 + q][m]; }
#pragma unroll
      for (int i = 0; i < 4; ++i)
#pragma unroll
        for (int j = 0; j < 4; ++j) acc[i][j] += a[i] * w[j];
    }
    // store transposed: S[kb-row j][ib-col i] = Lblk[i][j]
#pragma unroll
    for (int i = 0; i < 4; ++i)
#pragma unroll
      for (int j = 0; j < 4; ++j)
        S[(ko + tx * 4 + j) * CD + ro + ty * 4 + i] = acc[i][j];
  } else {
    const int ib = kb + blockIdx.y;            // 1..nrem -> kb+1..31
    const int jb = kb + 1 + blockIdx.x;
    if (jb > ib) return;
    if (blockIdx.y == 1 && blockIdx.x == 0) return;   // (kb+1,kb+1): lookahead's
    const long io = (long)ib * 64, jo = (long)jb * 64;
    const float* Kp = KinvA + (long)kb * 4096;
    for (int t = tid; t < 4096; t += 256) {
      int r = t >> 6, c = t & 63;
      As[r][c] = S[(io + r) * CD + ko + c];
      Bs[r][c] = Kp[t];
    }
    __syncthreads();
    float acc[4][4];
#pragma unroll
    for (int i = 0; i < 4; ++i)
#pragma unroll
      for (int j = 0; j < 4; ++j) acc[i][j] = 0.f;
    for (int m = 0; m < 64; ++m) {
      float a[4], k2[4];
#pragma unroll
      for (int q = 0; q < 4; ++q) { a[q] = As[ty * 4 + q][m]; k2[q] = Bs[m][tx * 4 + q]; }
#pragma unroll
      for (int i = 0; i < 4; ++i)
#pragma unroll
        for (int j = 0; j < 4; ++j) acc[i][j] += a[i] * k2[j];
    }
#pragma unroll
    for (int i = 0; i < 4; ++i)
#pragma unroll
      for (int j = 0; j < 4; ++j) Ts[ty * 4 + i][tx * 4 + j] = acc[i][j];
    __syncthreads();
    for (int t = tid; t < 4096; t += 256) {
      int r = t >> 6, c = t & 63;
      Bs[r][c] = S[(jo + r) * CD + ko + c];
    }
    __syncthreads();
    float acc2[4][4];
#pragma unroll
    for (int i = 0; i < 4; ++i)
#pragma unroll
      for (int j = 0; j < 4; ++j) acc2[i][j] = 0.f;
    for (int m = 0; m < 64; ++m) {
      float t2[4], b2[4];
#pragma unroll
      for (int q = 0; q < 4; ++q) { t2[q] = Ts[ty * 4 + q][m]; b2[q] = Bs[tx * 4 + q][m]; }
#pragma unroll
      for (int i = 0; i < 4; ++i)
#pragma unroll
        for (int j = 0; j < 4; ++j) acc2[i][j] += t2[i] * b2[j];
    }
#pragma unroll
    for (int i = 0; i < 4; ++i)
#pragma unroll
      for (int j = 0; j < 4; ++j)
        S[(io + ty * 4 + i) * CD + jo + tx * 4 + j] -= acc2[i][j];
  }
}

// ============================================================================
// W = inv(L) by block doubling. Level s: for each pair p (b = 2ps):
//   W[b+s.., b..] = -Wc * Bm * Wa,  Bm stored transposed in S's upper mirror.
// winv_tn: T[p] = Bmt^T * Wa ; winv_nn: W21 = -Wc * T[p].
// ============================================================================
__global__ __launch_bounds__(256) void winv_tn(
    const float* __restrict__ S, const float* __restrict__ W, float* __restrict__ T, int s)
{
  __shared__ float Ua[16][68];
  __shared__ float Wa[16][68];
  const int tid = threadIdx.x, tx = tid & 15, ty = tid >> 4;
  const int p = blockIdx.z, b = 2 * p * s;
  const int i0 = blockIdx.y * 64, j0 = blockIdx.x * 64;
  const int sr = tid >> 4, sc = (tid & 15) * 4;
  float acc[4][4];
#pragma unroll
  for (int i = 0; i < 4; ++i)
#pragma unroll
    for (int j = 0; j < 4; ++j) acc[i][j] = 0.f;

  for (int k0 = 0; k0 < s; k0 += 16) {
    __syncthreads();
    {
      float4 u = *(const float4*)(S + (long)(b + k0 + sr) * CD + (b + s) + i0 + sc);
      *(float4*)&Ua[sr][sc] = u;
      float4 w = *(const float4*)(W + (long)(b + k0 + sr) * 2048 + b + j0 + sc);
      *(float4*)&Wa[sr][sc] = w;
    }
    __syncthreads();
#pragma unroll
    for (int kk = 0; kk < 16; ++kk) {
      float a[4], w2[4];
#pragma unroll
      for (int q = 0; q < 4; ++q) { a[q] = Ua[kk][ty * 4 + q]; w2[q] = Wa[kk][tx * 4 + q]; }
#pragma unroll
      for (int i = 0; i < 4; ++i)
#pragma unroll
        for (int j = 0; j < 4; ++j) acc[i][j] += a[i] * w2[j];
    }
  }
  float* Tp = T + (long)p * s * s;
#pragma unroll
  for (int i = 0; i < 4; ++i)
#pragma unroll
    for (int j = 0; j < 4; ++j)
      Tp[(long)(i0 + ty * 4 + i) * s + j0 + tx * 4 + j] = acc[i][j];
}

__global__ __launch_bounds__(256) void winv_nn(
    float* __restrict__ W, const float* __restrict__ T, int s)
{
  __shared__ float Wc[64][20];
  __shared__ float Tt[16][68];
  const int tid = threadIdx.x, tx = tid & 15, ty = tid >> 4;
  const int p = blockIdx.z, b = 2 * p * s, bs = b + s;
  const int i0 = blockIdx.y * 64, j0 = blockIdx.x * 64;
  const float* Tp = T + (long)p * s * s;
  float acc[4][4];
#pragma unroll
  for (int i = 0; i < 4; ++i)
#pragma unroll
    for (int j = 0; j < 4; ++j) acc[i][j] = 0.f;

  for (int k0 = 0; k0 < s; k0 += 16) {
    __syncthreads();
    {
      const int wr = tid >> 2, wc = (tid & 3) * 4;
      float4 a = *(const float4*)(W + (long)(bs + i0 + wr) * 2048 + bs + k0 + wc);
      *(float4*)&Wc[wr][wc] = a;
      const int tr = tid >> 4, tc = (tid & 15) * 4;
      float4 t2 = *(const float4*)(Tp + (long)(k0 + tr) * s + j0 + tc);
      *(float4*)&Tt[tr][tc] = t2;
    }
    __syncthreads();
#pragma unroll
    for (int kk = 0; kk < 16; ++kk) {
      float a[4], t3[4];
#pragma unroll
      for (int q = 0; q < 4; ++q) { a[q] = Wc[ty * 4 + q][kk]; t3[q] = Tt[kk][tx * 4 + q]; }
#pragma unroll
      for (int i = 0; i < 4; ++i)
#pragma unroll
        for (int j = 0; j < 4; ++j) acc[i][j] += a[i] * t3[j];
    }
  }
#pragma unroll
  for (int i = 0; i < 4; ++i)
#pragma unroll
    for (int j = 0; j < 4; ++j)
      W[(long)(bs + i0 + ty * 4 + i) * 2048 + b + j0 + tx * 4 + j] = -acc[i][j];
}

// ============================================================================
// Host launch.
// ws (80.1 MB): vec 128K | R1: SYM fp32 16M | R2 32M: Cp (16M atomic fp32) /
//   SYMh transient, then W fp32 @+1M, W_f16 @+17M, T @+25M, KinvA @+29M (512K)
//   | R3: BIG f16 32M.
// d_out: Mt_h [0:32M), slotB [32M:64M) -> Xtr [0:32M) -> final Q fp32 (64M).
// ============================================================================
extern "C" void kernel_launch(void* const* d_in, const int* in_sizes, int n_in,
                              void* d_out, int out_size, void* d_ws, size_t ws_size,
                              hipStream_t stream)
{
  const float* s_in  = (const float*)d_in[0];
  const float* sgrad = (const float*)d_in[1];
  const float* L_h0  = (const float*)d_in[2];
  const float* L_c0  = (const float*)d_in[3];
  const float* R_h0  = (const float*)d_in[4];
  const float* R_c0  = (const float*)d_in[5];
  const float* L_bef = (const float*)d_in[6];
  const float* R_bef = (const float*)d_in[7];
  const float* Wih0  = (const float*)d_in[8];
  const float* Whh0  = (const float*)d_in[9];
  const float* bih0  = (const float*)d_in[10];
  const float* bhh0  = (const float*)d_in[11];
  const float* Wih1  = (const float*)d_in[12];
  const float* Whh1  = (const float*)d_in[13];
  const float* bih1  = (const float*)d_in[14];
  const float* bhh1  = (const float*)d_in[15];
  const float* L_W   = (const float*)d_in[16];
  const float* L_b   = (const float*)d_in[17];
  const float* R_W   = (const float*)d_in[18];
  const float* R_b   = (const float*)d_in[19];

  float* out = (float*)d_out;
  char*  ws  = (char*)d_ws;

  const size_t SYM_OFF = (size_t)1 << 17;
  const size_t OVL_OFF = SYM_OFF + ((size_t)16 << 20);
  const size_t BIG_OFF = OVL_OFF + ((size_t)32 << 20);
  float* vec  = (float*)ws;
  float* sums = vec;
  float* ggt  = vec + 4;
  float* gtg  = ggt + RD;
  float* lpre = gtg + CD;
  float* rpre = lpre + RD;
  float*     SYM  = (float*)(ws + SYM_OFF);
  float*     Cp   = (float*)(ws + OVL_OFF);
  _Float16*  SYMh = (_Float16*)(ws + OVL_OFF);
  float*     Wf   = (float*)(ws + OVL_OFF + ((size_t)1 << 20));    // inv(L), 16M
  _Float16*  Wh   = (_Float16*)(ws + OVL_OFF + ((size_t)17 << 20)); // 8M
  float*     Tbuf = (float*)(ws + OVL_OFF + ((size_t)25 << 20));   // 4M
  float*     KinvA= (float*)(ws + OVL_OFF + ((size_t)29 << 20));   // 32 x 16K
  _Float16*  BIG  = (_Float16*)(ws + BIG_OFF);                     // Gt->Pt->Xt->Qh

  _Float16* Mt_h  = (_Float16*)d_out;
  _Float16* slotB = Mt_h + (long)CD * RD;
  _Float16* Xtr   = (_Float16*)d_out;    // overwrites Mt_h (dead by then)

  hipMemsetAsync(vec, 0, (4 + RD) * sizeof(float), stream);
  hipMemsetAsync(Cp, 0, (size_t)CD * CD * sizeof(float), stream);  // gemm #1 atomic acc

  const dim3 blk(256);
  const dim3 gK8(16, 16, 8);    // M=N=2048, K=8192, split-K 8 (atomicAdd)
  const dim3 gK2(64, 16, 1);    // M=2048, N=8192, K=2048
  const dim3 gSym(32, 32);
  const int  castBlocks = (CD * RD / 4) / 256;

  cast_f16<<<castBlocks, blk, 0, stream>>>(s_in, Mt_h);
  cast_f16<<<castBlocks, blk, 0, stream>>>(sgrad, slotB);

  // Asym = 0.05 * sym(Mt * Sgt^T)
  gemm_nt_f16<<<gK8, blk, 0, stream>>>(Mt_h, slotB, Cp, nullptr, nullptr, nullptr,
                                       CD, CD, RD, 8, 0.f, 0.f, 1.f);
  sym_combine<<<gSym, blk, 0, stream>>>(Cp, SYM, CD, 1, 0.05f);
  cast_f16<<<(CD * CD / 4) / 256, blk, 0, stream>>>(SYM, SYMh);

  transpose_cast_f16<<<dim3(RD / 64, CD / 64), blk, 0, stream>>>(s_in, slotB); // Mtr

  // Gt = 0.1*Sgt - Asym*Mt
  gemm_nt_f16<<<gK2, blk, 0, stream>>>(SYMh, slotB, nullptr, BIG, sgrad, nullptr,
                                       CD, RD, CD, 1, 0.1f, 0.f, -1.f);

  row_sumsq<<<CD, blk, 0, stream>>>(BIG, gtg, 1.f / (float)RD);
  col_sumsq<<<dim3(RD / 256, CD / 256), blk, 0, stream>>>(BIG, ggt);

  lstm_head<<<RD / 256, blk, 0, stream>>>(ggt, RD, L_h0, L_c0, Wih0, Whh0, bih0, bhh0,
                                          Wih1, Whh1, bih1, bhh1, L_W, L_b, lpre, &sums[0]);
  lstm_head<<<CD / 256, blk, 0, stream>>>(gtg, CD, R_h0, R_c0, Wih0, Whh0, bih0, bhh0,
                                          Wih1, Whh1, bih1, bhh1, R_W, R_b, rpre, &sums[1]);

  scale_P<<<(CD * (RD / 4)) / 256, blk, 0, stream>>>(BIG, lpre, rpre, L_bef, R_bef, sums);

  // Bsym = 0.5 * sym(Mt * Pt^T)
  hipMemsetAsync(Cp, 0, (size_t)CD * CD * sizeof(float), stream);
  gemm_nt_f16<<<gK8, blk, 0, stream>>>(Mt_h, BIG, Cp, nullptr, nullptr, nullptr,
                                       CD, CD, RD, 8, 0.f, 0.f, 1.f);
  sym_combine<<<gSym, blk, 0, stream>>>(Cp, SYM, CD, 1, 0.5f);
  cast_f16<<<(CD * CD / 4) / 256, blk, 0, stream>>>(SYM, SYMh);

  // Xt = Mt - Pt + Bsym*Mt (in place)
  gemm_nt_f16<<<gK2, blk, 0, stream>>>(SYMh, slotB, nullptr, BIG, s_in, BIG,
                                       CD, RD, CD, 1, 1.f, -1.f, 1.f);

  // Gram S = 0.5 * sym(Xt * Xt^T)
  hipMemsetAsync(Cp, 0, (size_t)CD * CD * sizeof(float), stream);
  gemm_nt_f16<<<gK8, blk, 0, stream>>>(BIG, BIG, Cp, nullptr, nullptr, nullptr,
                                       CD, CD, RD, 8, 0.f, 0.f, 1.f);
  sym_combine<<<gSym, blk, 0, stream>>>(Cp, SYM, CD, 1, 0.5f);

  hipMemsetAsync(Wf, 0, (size_t)CD * CD * sizeof(float), stream);
  transpose_f16<<<dim3(RD / 64, CD / 64), blk, 0, stream>>>(BIG, Xtr);

  // Cholesky ladder with lookahead fusion: seed potrf(0), then 31 fused
  // dispatches each doing {panel(kb), trail(kb), potrf(kb+1)} concurrently.
  potrf_seed<<<1, blk, 0, stream>>>(SYM, Wf, KinvA);
  for (int kb = 0; kb < 31; ++kb) {
    const int nrem = 31 - kb;
    ptstep_f<<<dim3(nrem, nrem + 2), blk, 0, stream>>>(SYM, Wf, KinvA, kb);
  }

  // W = inv(L) by doubling: 5 levels x 2 dispatches
  for (int lev = 0; lev < 5; ++lev) {
    const int s = 64 << lev, npairs = 16 >> lev;
    const dim3 g(s / 64, s / 64, npairs);
    winv_tn<<<g, blk, 0, stream>>>(SYM, Wf, Tbuf, s);
    winv_nn<<<g, blk, 0, stream>>>(Wf, Tbuf, s);
  }

  // Qh = W * Xt  (NT: A = W_f16 rows, B = Xtr rows), then upcast to d_out
  cast_f16<<<(CD * CD / 4) / 256, blk, 0, stream>>>(Wf, Wh);
  gemm_nt_f16<<<gK2, blk, 0, stream>>>(Wh, Xtr, nullptr, BIG, nullptr, nullptr,
                                       CD, RD, CD, 1, 0.f, 0.f, 1.f);
  cast_f32<<<(CD * RD / 8) / 256, blk, 0, stream>>>(BIG, out);
}

// Round 5
// 3090.455 us; speedup vs baseline: 1.0408x; 1.0408x over previous
//
#include <hip/hip_runtime.h>
#include <math.h>

#define RD 8192   // r (long dim, contiguous in storage)
#define CD 2048   // c (short dim, rows in storage)

typedef _Float16 f16x8 __attribute__((ext_vector_type(8)));
typedef _Float16 f16x4 __attribute__((ext_vector_type(4)));
typedef float    f32x4 __attribute__((ext_vector_type(4)));

#define GLOBAL_AS __attribute__((address_space(1)))
#define LDS_AS    __attribute__((address_space(3)))

// ============================================================================
// f16 MFMA GEMM (NT): C[i][j] = sum_k A[i*K+k] * B[j*K+k], fp32 accumulate.
// R5: 256x256 tile, 8 waves (2Mx4N), BK=32, double-buffered 2-phase loop
// (R3's proven race-free sync structure). 32 MFMA per K-step per wave vs 16
// at the old 128^2 tile -- per-step LDS/barrier/staging overhead amortized
// over 2x FLOPs (m93/m230 tile-scaling lever).
// mode A (Cp != 0): split-K partial sums via atomicAdd into zeroed fp32 C.
// mode B (Cp == 0): Of16[i][j] = f16( sgn*acc + beta*Dg[ij] + gamma*Eg[ij] )
// ============================================================================
__global__ __launch_bounds__(512, 2) void gemm_nt_f16(
    const _Float16* __restrict__ A, const _Float16* __restrict__ B,
    float* __restrict__ Cp, _Float16* __restrict__ Of16,
    const float* __restrict__ Dg, const _Float16* __restrict__ Eg,
    int M, int N, int K, int ksplit, float beta, float gamma, float sgn)
{
  __shared__ __align__(1024) _Float16 As[2][256 * 32];
  __shared__ __align__(1024) _Float16 Bs[2][256 * 32];
  const int tid = threadIdx.x;
  const int wave = tid >> 6, lane = tid & 63;
  const int wy = wave >> 2, wx = wave & 3;          // 2 x 4 wave grid
  const int bi = blockIdx.y * 256, bj = blockIdx.x * 256;
  const int kchunk = K / ksplit;
  const long k0 = (long)blockIdx.z * kchunk;

  f32x4 acc[8][4];
#pragma unroll
  for (int i = 0; i < 8; ++i)
#pragma unroll
    for (int j = 0; j < 4; ++j) acc[i][j] = (f32x4){0.f, 0.f, 0.f, 0.f};

  const int srow = wave * 16 + (lane >> 2);         // 0..127
  const int skof = (lane & 3) * 8;
  const _Float16* aA = A + (long)(bi + srow) * K + k0 + skof;
  const _Float16* aB = B + (long)(bj + srow) * K + k0 + skof;
  const int ldso = wave * 16 * 32;

  // 4 global_load_lds per thread per STAGE (2 for A, 2 for B); q covers
  // row halves 0-127 / 128-255.
#define STAGE(buf, kt)                                                         \
  {                                                                            \
    _Float16* lA = &As[buf][ldso];                                             \
    _Float16* lB = &Bs[buf][ldso];                                             \
    _Pragma("unroll")                                                          \
    for (int q = 0; q < 2; ++q) {                                              \
      __builtin_amdgcn_global_load_lds(                                        \
          (const GLOBAL_AS unsigned int*)(aA + (long)q * 128 * K + (kt)),      \
          (LDS_AS unsigned int*)(lA + q * 128 * 32), 16, 0, 0);                \
      __builtin_amdgcn_global_load_lds(                                        \
          (const GLOBAL_AS unsigned int*)(aB + (long)q * 128 * K + (kt)),      \
          (LDS_AS unsigned int*)(lB + q * 128 * 32), 16, 0, 0);                \
    }                                                                          \
  }

  const int fr = lane & 15;
  const int fk = (lane >> 4) * 8;

  STAGE(0, 0);
  __syncthreads();
  int cur = 0;
  for (int kt = 0; kt < kchunk; kt += 32) {
    if (kt + 32 < kchunk) STAGE(cur ^ 1, kt + 32);   // async prefetch next tile

    f16x8 af[8], bf[4];
#pragma unroll
    for (int t = 0; t < 8; ++t)
      af[t] = *(const f16x8*)(&As[cur][(wy * 128 + t * 16 + fr) * 32 + fk]);
#pragma unroll
    for (int t = 0; t < 4; ++t)
      bf[t] = *(const f16x8*)(&Bs[cur][(wx * 64 + t * 16 + fr) * 32 + fk]);
#pragma unroll
    for (int mt = 0; mt < 8; ++mt)
#pragma unroll
      for (int nt = 0; nt < 4; ++nt)
        acc[mt][nt] = __builtin_amdgcn_mfma_f32_16x16x32_f16(af[mt], bf[nt], acc[mt][nt], 0, 0, 0);

    __syncthreads();   // staged loads resident + all reads of cur done
    cur ^= 1;
  }
#undef STAGE

  const int quad = lane >> 4, fc = lane & 15;
  if (Cp) {
#pragma unroll
    for (int mt = 0; mt < 8; ++mt)
#pragma unroll
      for (int nt = 0; nt < 4; ++nt) {
        const int col = bj + wx * 64 + nt * 16 + fc;
#pragma unroll
        for (int reg = 0; reg < 4; ++reg) {
          const int row = bi + wy * 128 + mt * 16 + quad * 4 + reg;
          atomicAdd(&Cp[(long)row * N + col], acc[mt][nt][reg]);
        }
      }
  } else {
#pragma unroll
    for (int mt = 0; mt < 8; ++mt)
#pragma unroll
      for (int nt = 0; nt < 4; ++nt) {
        const int col = bj + wx * 64 + nt * 16 + fc;
#pragma unroll
        for (int reg = 0; reg < 4; ++reg) {
          const int row = bi + wy * 128 + mt * 16 + quad * 4 + reg;
          const long off = (long)row * N + col;
          float v = sgn * acc[mt][nt][reg];
          if (Dg) v += beta * Dg[off];
          if (Eg) v += gamma * (float)Eg[off];
          Of16[off] = (_Float16)v;
        }
      }
  }
}

// ============================================================================
// sym_combine: out[i][j] = scale * sum_z (Cp[z][i][j] + Cp[z][j][i]), n x n fp32.
// ============================================================================
__global__ __launch_bounds__(256) void sym_combine(
    const float* __restrict__ Cp, float* __restrict__ out, int n, int nsplit, float scale)
{
  __shared__ float Ts[64][68];
  const int tid = threadIdx.x;
  const int tx = tid & 15, ty = tid >> 4;
  const int bi = blockIdx.y * 64, bj = blockIdx.x * 64;
  float acc[4][4];
#pragma unroll
  for (int i = 0; i < 4; ++i)
#pragma unroll
    for (int j = 0; j < 4; ++j) acc[i][j] = 0.f;

  for (int s = 0; s < nsplit; ++s) {
    const float* C = Cp + (long)s * n * n;
#pragma unroll
    for (int i = 0; i < 4; ++i) {
      float4 v = *(const float4*)(C + (long)(bi + ty * 4 + i) * n + bj + tx * 4);
      acc[i][0] += v.x; acc[i][1] += v.y; acc[i][2] += v.z; acc[i][3] += v.w;
    }
    __syncthreads();
#pragma unroll
    for (int i = 0; i < 4; ++i) {
      float4 w = *(const float4*)(C + (long)(bj + ty * 4 + i) * n + bi + tx * 4);
      *(float4*)&Ts[ty * 4 + i][tx * 4] = w;
    }
    __syncthreads();
#pragma unroll
    for (int i = 0; i < 4; ++i)
#pragma unroll
      for (int j = 0; j < 4; ++j) acc[i][j] += Ts[tx * 4 + j][ty * 4 + i];
  }
#pragma unroll
  for (int i = 0; i < 4; ++i) {
    float4 v; v.x = scale * acc[i][0]; v.y = scale * acc[i][1]; v.z = scale * acc[i][2]; v.w = scale * acc[i][3];
    *(float4*)(out + (long)(bi + ty * 4 + i) * n + bj + tx * 4) = v;
  }
}

// ============================================================================
// Casts / transposes.
// ============================================================================
__global__ __launch_bounds__(256) void cast_f16(const float* __restrict__ s, _Float16* __restrict__ d)
{
  const long i = ((long)blockIdx.x * 256 + threadIdx.x) * 4;
  float4 v = *(const float4*)(s + i);
  f16x4 o; o[0] = (_Float16)v.x; o[1] = (_Float16)v.y; o[2] = (_Float16)v.z; o[3] = (_Float16)v.w;
  *(f16x4*)(d + i) = o;
}

__global__ __launch_bounds__(256) void cast_f32(const _Float16* __restrict__ s, float* __restrict__ d)
{
  const long i = ((long)blockIdx.x * 256 + threadIdx.x) * 8;
  f16x8 v = *(const f16x8*)(s + i);
  float4 a, b;
  a.x = (float)v[0]; a.y = (float)v[1]; a.z = (float)v[2]; a.w = (float)v[3];
  b.x = (float)v[4]; b.y = (float)v[5]; b.z = (float)v[6]; b.w = (float)v[7];
  *(float4*)(d + i) = a;
  *(float4*)(d + i + 4) = b;
}

__global__ __launch_bounds__(256) void transpose_cast_f16(
    const float* __restrict__ src, _Float16* __restrict__ dst)
{
  __shared__ float T[64][65];
  const int tid = threadIdx.x, tx = tid & 15, ty = tid >> 4;
  const int r0 = blockIdx.x * 64, c0 = blockIdx.y * 64;
#pragma unroll
  for (int i = 0; i < 4; ++i) {
    float4 v = *(const float4*)(src + (long)(c0 + ty * 4 + i) * RD + r0 + tx * 4);
    T[ty * 4 + i][tx * 4 + 0] = v.x; T[ty * 4 + i][tx * 4 + 1] = v.y;
    T[ty * 4 + i][tx * 4 + 2] = v.z; T[ty * 4 + i][tx * 4 + 3] = v.w;
  }
  __syncthreads();
#pragma unroll
  for (int i = 0; i < 4; ++i) {
    f16x4 o;
#pragma unroll
    for (int j = 0; j < 4; ++j) o[j] = (_Float16)T[tx * 4 + j][ty * 4 + i];
    *(f16x4*)(dst + (long)(r0 + ty * 4 + i) * CD + c0 + tx * 4) = o;
  }
}

// f16 (CD x RD) -> f16 (RD x CD) transpose, 64x64 tiles
__global__ __launch_bounds__(256) void transpose_f16(
    const _Float16* __restrict__ src, _Float16* __restrict__ dst)
{
  __shared__ _Float16 T[64][72];
  const int tid = threadIdx.x;
  const int r0 = blockIdx.y * 64;   // src row (CD)
  const int c0 = blockIdx.x * 64;   // src col (RD)
  const int sr = tid >> 2, sc = (tid & 3) * 16;
  {
    f16x8 a = *(const f16x8*)(src + (long)(r0 + sr) * RD + c0 + sc);
    f16x8 b = *(const f16x8*)(src + (long)(r0 + sr) * RD + c0 + sc + 8);
    *(f16x8*)&T[sr][sc] = a;
    *(f16x8*)&T[sr][sc + 8] = b;
  }
  __syncthreads();
  {
    f16x8 a, b;
#pragma unroll
    for (int q = 0; q < 8; ++q) { a[q] = T[sc + q][sr]; b[q] = T[sc + 8 + q][sr]; }
    *(f16x8*)(dst + (long)(c0 + sr) * CD + r0 + sc) = a;
    *(f16x8*)(dst + (long)(c0 + sr) * CD + r0 + sc + 8) = b;
  }
}

// ============================================================================
// Diag-of-Gram reductions on f16 G.
// ============================================================================
__global__ __launch_bounds__(256) void row_sumsq(const _Float16* __restrict__ G, float* __restrict__ out, float inv)
{
  __shared__ float red[256];
  const int tid = threadIdx.x;
  const _Float16* row = G + (long)blockIdx.x * RD;
  float s = 0.f;
  for (int c = tid * 8; c < RD; c += 2048) {
    f16x8 v = *(const f16x8*)(row + c);
#pragma unroll
    for (int u = 0; u < 8; ++u) { float f = (float)v[u]; s += f * f; }
  }
  red[tid] = s; __syncthreads();
  for (int off = 128; off > 0; off >>= 1) { if (tid < off) red[tid] += red[tid + off]; __syncthreads(); }
  if (tid == 0) out[blockIdx.x] = red[0] * inv;
}

__global__ __launch_bounds__(256) void col_sumsq(const _Float16* __restrict__ G, float* __restrict__ out)
{
  const int rr = blockIdx.x * 256 + threadIdx.x;
  const int cc0 = blockIdx.y * 256;
  float s = 0.f;
  for (int i = 0; i < 256; ++i) {
    float v = (float)G[(long)(cc0 + i) * RD + rr];
    s += v * v;
  }
  atomicAdd(&out[rr], s * (1.f / (float)CD));
}

// ============================================================================
// 2-layer LSTM single step + linear head.
// ============================================================================
__device__ __forceinline__ float sigm_(float x) { return 1.f / (1.f + __expf(-x)); }
__device__ __forceinline__ float tanh_(float x) { float e = __expf(2.f * x); return 1.f - 2.f / (e + 1.f); }

__global__ __launch_bounds__(256) void lstm_head(
    const float* __restrict__ diag, int B,
    const float* __restrict__ h0, const float* __restrict__ c0,
    const float* __restrict__ Wih0, const float* __restrict__ Whh0,
    const float* __restrict__ bih0, const float* __restrict__ bhh0,
    const float* __restrict__ Wih1, const float* __restrict__ Whh1,
    const float* __restrict__ bih1, const float* __restrict__ bhh1,
    const float* __restrict__ HW, const float* __restrict__ Hb,
    float* __restrict__ pre, float* __restrict__ sum_out)
{
  __shared__ float w0[80], wh0[1600], b0[80], wi1[1600], wh1[1600], b1[80], hw[20];
  __shared__ float red[256];
  const int tid = threadIdx.x;
  for (int i = tid; i < 80; i += 256) { w0[i] = Wih0[i]; b0[i] = bih0[i] + bhh0[i]; b1[i] = bih1[i] + bhh1[i]; }
  for (int i = tid; i < 1600; i += 256) { wh0[i] = Whh0[i]; wi1[i] = Wih1[i]; wh1[i] = Whh1[i]; }
  if (tid < 20) hw[tid] = HW[tid];
  __syncthreads();

  const int b = blockIdx.x * 256 + tid;
  const float d = diag[b];
  float x = logf(fabsf(d)) * 0.1f;
  x = fminf(fmaxf(x, -1.f), 1.f);

  const float* h0p = h0 + (long)b * 20;
  const float* c0p = c0 + (long)b * 20;
  const float* h1p = h0 + (long)B * 20 + (long)b * 20;
  const float* c1p = c0 + (long)B * 20 + (long)b * 20;

  float h0r[20], hA[20];
#pragma unroll
  for (int m = 0; m < 20; ++m) h0r[m] = h0p[m];
#pragma unroll
  for (int h = 0; h < 20; ++h) {
    float gi = w0[h] * x + b0[h];
    float gf = w0[20 + h] * x + b0[20 + h];
    float gg = w0[40 + h] * x + b0[40 + h];
    float go = w0[60 + h] * x + b0[60 + h];
#pragma unroll
    for (int m = 0; m < 20; ++m) {
      const float hm = h0r[m];
      gi += wh0[h * 20 + m] * hm;
      gf += wh0[(20 + h) * 20 + m] * hm;
      gg += wh0[(40 + h) * 20 + m] * hm;
      go += wh0[(60 + h) * 20 + m] * hm;
    }
    const float cc = sigm_(gf) * c0p[h] + sigm_(gi) * tanh_(gg);
    hA[h] = sigm_(go) * tanh_(cc);
  }
  float h1r[20];
#pragma unroll
  for (int m = 0; m < 20; ++m) h1r[m] = h1p[m];
  float pr = 0.f;
#pragma unroll
  for (int h = 0; h < 20; ++h) {
    float gi = b1[h], gf = b1[20 + h], gg = b1[40 + h], go = b1[60 + h];
#pragma unroll
    for (int m = 0; m < 20; ++m) {
      const float am = hA[m], hm = h1r[m];
      gi += wi1[h * 20 + m] * am + wh1[h * 20 + m] * hm;
      gf += wi1[(20 + h) * 20 + m] * am + wh1[(20 + h) * 20 + m] * hm;
      gg += wi1[(40 + h) * 20 + m] * am + wh1[(40 + h) * 20 + m] * hm;
      go += wi1[(60 + h) * 20 + m] * am + wh1[(60 + h) * 20 + m] * hm;
    }
    const float cc = sigm_(gf) * c1p[h] + sigm_(gi) * tanh_(gg);
    pr += sigm_(go) * tanh_(cc) * hw[h];
  }
  pr = (pr + Hb[0]) * 0.1f;
  pre[b] = pr;

  red[tid] = pr; __syncthreads();
  for (int off = 128; off > 0; off >>= 1) { if (tid < off) red[tid] += red[tid + off]; __syncthreads(); }
  if (tid == 0) atomicAdd(sum_out, red[0]);
}

// ============================================================================
// Pt[cc][rr] = Rv(cc) * Gt[cc][rr] * Lv(rr), in place on f16.
// ============================================================================
__global__ __launch_bounds__(256) void scale_P(
    _Float16* __restrict__ G, const float* __restrict__ lpre, const float* __restrict__ rpre,
    const float* __restrict__ Lbef, const float* __restrict__ Rbef, const float* __restrict__ sums)
{
  const long id4 = ((long)blockIdx.x * 256 + threadIdx.x) * 4;
  const int cc = (int)(id4 >> 13);
  const int rr = (int)(id4 & (RD - 1));
  const float meanl = sums[0] * (1.f / (float)RD);
  const float meanr = sums[1] * (1.f / (float)CD);
  const float rv = fmaxf(rpre[cc] - meanr + 1.f, Rbef[cc]);
  f16x4 g = *(f16x4*)(G + id4);
  float4 lp = *(const float4*)(lpre + rr);
  float4 lb = *(const float4*)(Lbef + rr);
  g[0] = (_Float16)((float)g[0] * rv * fmaxf(lp.x - meanl + 1.f, lb.x));
  g[1] = (_Float16)((float)g[1] * rv * fmaxf(lp.y - meanl + 1.f, lb.y));
  g[2] = (_Float16)((float)g[2] * rv * fmaxf(lp.z - meanl + 1.f, lb.z));
  g[3] = (_Float16)((float)g[3] * rv * fmaxf(lp.w - meanl + 1.f, lb.w));
  *(f16x4*)(G + id4) = g;
}

// ============================================================================
// potrf_block_dev: factor the 64x64 diag block d of S, optionally first
// applying step-kprev's trailing update to it (lookahead fusion).
// Produces: W diag block d  = inv(L_dd)   (full 64x64 incl. upper zeros)
//           KinvA[d]        = inv(L_dd)^T inv(L_dd)
//
// Parallel algorithm (verified R3): deferred-scale right-looking Cholesky
// (64 barriers, rank-1 updates over 256 threads) + inv(L) by in-LDS block
// doubling (4 parallel 16x16 serial inverses, then 16->32, 32->64 matmuls).
// ============================================================================
__device__ __forceinline__ void potrf_block_dev(
    float* __restrict__ S, float* __restrict__ W, float* __restrict__ KinvA,
    int d, int kprev, float (*Ls)[68], float (*Ws)[68], float (*Ts)[68])
{
  const int tid = threadIdx.x;
  const int tx = tid & 15, ty = tid >> 4;
  const long dofs = (long)d * 64;

  for (int t = tid; t < 4096; t += 256) {
    int r = t >> 6, c = t & 63;
    Ls[r][c] = S[(dofs + r) * CD + dofs + c];
  }

  if (kprev >= 0) {
    const float* Kp = KinvA + (long)kprev * 4096;
    const long ko = (long)kprev * 64;
    for (int t = tid; t < 4096; t += 256) {
      int r = t >> 6, c = t & 63;
      Ts[r][c] = S[(dofs + r) * CD + ko + c];   // P = S(d, kprev), pre-step
      Ws[r][c] = Kp[t];                          // Kinv (symmetric)
    }
    __syncthreads();
    float u[4][4];
#pragma unroll
    for (int i = 0; i < 4; ++i)
#pragma unroll
      for (int j = 0; j < 4; ++j) u[i][j] = 0.f;
    for (int m = 0; m < 64; ++m) {
      float a[4], k2[4];
#pragma unroll
      for (int q = 0; q < 4; ++q) { a[q] = Ts[ty * 4 + q][m]; k2[q] = Ws[m][tx * 4 + q]; }
#pragma unroll
      for (int i = 0; i < 4; ++i)
#pragma unroll
        for (int j = 0; j < 4; ++j) u[i][j] += a[i] * k2[j];
    }
    __syncthreads();
#pragma unroll
    for (int i = 0; i < 4; ++i)
#pragma unroll
      for (int j = 0; j < 4; ++j) Ws[ty * 4 + i][tx * 4 + j] = u[i][j];   // U = P*Kinv
    __syncthreads();
    // Ls -= U * P^T   (result stays symmetric)
    float acc[4][4];
#pragma unroll
    for (int i = 0; i < 4; ++i)
#pragma unroll
      for (int j = 0; j < 4; ++j) acc[i][j] = 0.f;
    for (int m = 0; m < 64; ++m) {
      float a[4], b2[4];
#pragma unroll
      for (int q = 0; q < 4; ++q) { a[q] = Ws[ty * 4 + q][m]; b2[q] = Ts[tx * 4 + q][m]; }
#pragma unroll
      for (int i = 0; i < 4; ++i)
#pragma unroll
        for (int j = 0; j < 4; ++j) acc[i][j] += a[i] * b2[j];
    }
#pragma unroll
    for (int i = 0; i < 4; ++i)
#pragma unroll
      for (int j = 0; j < 4; ++j) Ls[ty * 4 + i][tx * 4 + j] -= acc[i][j];
  }

  // --- 1. deferred-scale right-looking Cholesky (lower triangle of Ls) -----
  for (int j = 0; j < 64; ++j) {
    __syncthreads();                                 // step j-1 writes visible
    const float invd = 1.f / Ls[j][j];
    for (int i = j + 1 + ty; i < 64; i += 16) {
      const float vi = Ls[i][j] * invd;
      for (int c = j + 1 + tx; c <= i; c += 16)
        Ls[i][c] -= vi * Ls[c][j];
    }
  }
  __syncthreads();
  if (tid < 64) Ts[0][tid] = 1.f / sqrtf(Ls[tid][tid]);   // rsqrt of pivots
  __syncthreads();
  for (int t = tid; t < 4096; t += 256) {            // scale: L[i][j]=Ls[i][j]*rs[j]
    int r = t >> 6, c = t & 63;
    if (c <= r) Ls[r][c] *= Ts[0][c];
  }
  // zero Ws (upper zeros needed downstream)
  for (int t = tid; t < 4096; t += 256) { int r = t >> 6, c = t & 63; Ws[r][c] = 0.f; }
  __syncthreads();

  // --- 2a. four parallel 16x16 inverses (wave w -> diag block w) -----------
  {
    const int w = tid >> 6, l = tid & 63;
    if (l < 16) {
      const int o = w * 16, c = l;
      float wr[16];
#pragma unroll
      for (int m = 0; m < 16; ++m) {
        float s = 0.f;
#pragma unroll
        for (int k = 0; k < m; ++k) s += Ls[o + m][o + k] * wr[k];
        const float rli = 1.f / Ls[o + m][o + m];
        wr[m] = (m == c) ? rli : -s * rli;
      }
#pragma unroll
      for (int m = 0; m < 16; ++m) Ws[o + m][o + c] = (m < c) ? 0.f : wr[m];
    }
  }
  __syncthreads();

  // --- 2b. doubling 16->32: pairs p=0,1 at b0=32p:
  //     T = L21*W11 (16x16), W21 = -W22*T
  {
    for (int e = tid; e < 512; e += 256) {
      const int p = e >> 8, m = (e >> 4) & 15, c = e & 15, b0 = p * 32;
      float s = 0.f;
#pragma unroll
      for (int k = 0; k < 16; ++k) s += Ls[b0 + 16 + m][b0 + k] * Ws[b0 + k][b0 + c];
      Ts[p * 16 + m][c] = s;
    }
    __syncthreads();
    for (int e = tid; e < 512; e += 256) {
      const int p = e >> 8, m = (e >> 4) & 15, c = e & 15, b0 = p * 32;
      float s = 0.f;
#pragma unroll
      for (int k = 0; k < 16; ++k) s += Ws[b0 + 16 + m][b0 + 16 + k] * Ts[p * 16 + k][c];
      Ws[b0 + 16 + m][b0 + c] = -s;
    }
  }
  __syncthreads();

  // --- 2c. doubling 32->64: T2 = L21'*W11' (32x32), W21' = -W22'*T2 --------
  {
    for (int q = 0; q < 4; ++q) {
      const int e = tid + 256 * q, m = e >> 5, c = e & 31;
      float s = 0.f;
#pragma unroll
      for (int k = 0; k < 32; ++k) s += Ls[32 + m][k] * Ws[k][c];
      Ts[m][c] = s;
    }
    __syncthreads();
    for (int q = 0; q < 4; ++q) {
      const int e = tid + 256 * q, m = e >> 5, c = e & 31;
      float s = 0.f;
#pragma unroll
      for (int k = 0; k < 32; ++k) s += Ws[32 + m][32 + k] * Ts[k][c];
      Ws[32 + m][c] = -s;
    }
  }
  __syncthreads();

  // store W diag block (row-major, incl. upper zeros)
  for (int t = tid; t < 4096; t += 256) {
    int r = t >> 6, c = t & 63;
    W[(dofs + r) * 2048 + dofs + c] = Ws[r][c];
  }
  // KinvA[d] = W^T W : Kinv[a][b] = sum_m Ws[m][a] * Ws[m][b]
  {
    float acc[4][4];
#pragma unroll
    for (int i = 0; i < 4; ++i)
#pragma unroll
      for (int j = 0; j < 4; ++j) acc[i][j] = 0.f;
    for (int m = 0; m < 64; ++m) {
      float a[4], b2[4];
#pragma unroll
      for (int q = 0; q < 4; ++q) { a[q] = Ws[m][ty * 4 + q]; b2[q] = Ws[m][tx * 4 + q]; }
#pragma unroll
      for (int i = 0; i < 4; ++i)
#pragma unroll
        for (int j = 0; j < 4; ++j) acc[i][j] += a[i] * b2[j];
    }
    float* Kd = KinvA + (long)d * 4096;
#pragma unroll
    for (int i = 0; i < 4; ++i)
#pragma unroll
      for (int j = 0; j < 4; ++j)
        Kd[(ty * 4 + i) * 64 + tx * 4 + j] = acc[i][j];
  }
}

__global__ __launch_bounds__(256) void potrf_seed(
    float* __restrict__ S, float* __restrict__ W, float* __restrict__ KinvA)
{
  __shared__ float Ls[64][68];
  __shared__ float Ws[64][68];
  __shared__ float Ts[64][68];
  potrf_block_dev(S, W, KinvA, 0, -1, Ls, Ws, Ts);
}

// ============================================================================
// ptstep_f: fused panel + trailing update + lookahead potrf for step kb.
// by==0 (panel): L(ib,kb) = Spre(ib,kb)*Ws(kb)^T, stored TRANSPOSED in the
//   upper mirror S[kb-rows, ib-cols]. Pre-step reads only.
// 1<=by<=nrem (trail): S(ib,jb) -= Spre(ib,kb)*Kinv[kb]*Spre(jb,kb)^T.
//   Skips (kb+1,kb+1) — the lookahead block handles it.
// by==nrem+1, bx==0 (lookahead): self-update + factor diag kb+1, emit
//   W diag kb+1 and Kinv[kb+1] for the next dispatch.
// All roles read only column-kb pre-values + disjoint outputs -> race-free.
// ============================================================================
__global__ __launch_bounds__(256) void ptstep_f(
    float* __restrict__ S, float* __restrict__ W, float* __restrict__ KinvA, int kb)
{
  __shared__ float As[64][68];
  __shared__ float Bs[64][68];
  __shared__ float Ts[64][68];
  const int tid = threadIdx.x, tx = tid & 15, ty = tid >> 4;
  const long ko = (long)kb * 64;
  const int nrem = 31 - kb;

  if (blockIdx.y == (unsigned)(nrem + 1)) {
    if (blockIdx.x != 0) return;
    potrf_block_dev(S, W, KinvA, kb + 1, kb, As, Bs, Ts);
    return;
  }

  if (blockIdx.y == 0) {
    const int ib = kb + 1 + blockIdx.x;
    const long ro = (long)ib * 64;
    for (int t = tid; t < 4096; t += 256) {
      int r = t >> 6, c = t & 63;
      As[r][c] = S[(ro + r) * CD + ko + c];
      Bs[r][c] = W[(ko + r) * 2048 + ko + c];   // Ws = inv(Lkk)
    }
    __syncthreads();
    float acc[4][4];
#pragma unroll
    for (int i = 0; i < 4; ++i)
#pragma unroll
      for (int j = 0; j < 4; ++j) acc[i][j] = 0.f;
    for (int m = 0; m < 64; ++m) {
      float a[4], w[4];
#pragma unroll
      for (int q = 0; q < 4; ++q) { a[q] = As[ty * 4 + q][m]; w[q] = Bs[tx * 4 + q][m]; }
#pragma unroll
      for (int i = 0; i < 4; ++i)
#pragma unroll
        for (int j = 0; j < 4; ++j) acc[i][j] += a[i] * w[j];
    }
    // store transposed: S[kb-row j][ib-col i] = Lblk[i][j]
#pragma unroll
    for (int i = 0; i < 4; ++i)
#pragma unroll
      for (int j = 0; j < 4; ++j)
        S[(ko + tx * 4 + j) * CD + ro + ty * 4 + i] = acc[i][j];
  } else {
    const int ib = kb + blockIdx.y;            // 1..nrem -> kb+1..31
    const int jb = kb + 1 + blockIdx.x;
    if (jb > ib) return;
    if (blockIdx.y == 1 && blockIdx.x == 0) return;   // (kb+1,kb+1): lookahead's
    const long io = (long)ib * 64, jo = (long)jb * 64;
    const float* Kp = KinvA + (long)kb * 4096;
    for (int t = tid; t < 4096; t += 256) {
      int r = t >> 6, c = t & 63;
      As[r][c] = S[(io + r) * CD + ko + c];
      Bs[r][c] = Kp[t];
    }
    __syncthreads();
    float acc[4][4];
#pragma unroll
    for (int i = 0; i < 4; ++i)
#pragma unroll
      for (int j = 0; j < 4; ++j) acc[i][j] = 0.f;
    for (int m = 0; m < 64; ++m) {
      float a[4], k2[4];
#pragma unroll
      for (int q = 0; q < 4; ++q) { a[q] = As[ty * 4 + q][m]; k2[q] = Bs[m][tx * 4 + q]; }
#pragma unroll
      for (int i = 0; i < 4; ++i)
#pragma unroll
        for (int j = 0; j < 4; ++j) acc[i][j] += a[i] * k2[j];
    }
#pragma unroll
    for (int i = 0; i < 4; ++i)
#pragma unroll
      for (int j = 0; j < 4; ++j) Ts[ty * 4 + i][tx * 4 + j] = acc[i][j];
    __syncthreads();
    for (int t = tid; t < 4096; t += 256) {
      int r = t >> 6, c = t & 63;
      Bs[r][c] = S[(jo + r) * CD + ko + c];
    }
    __syncthreads();
    float acc2[4][4];
#pragma unroll
    for (int i = 0; i < 4; ++i)
#pragma unroll
      for (int j = 0; j < 4; ++j) acc2[i][j] = 0.f;
    for (int m = 0; m < 64; ++m) {
      float t2[4], b2[4];
#pragma unroll
      for (int q = 0; q < 4; ++q) { t2[q] = Ts[ty * 4 + q][m]; b2[q] = Bs[tx * 4 + q][m]; }
#pragma unroll
      for (int i = 0; i < 4; ++i)
#pragma unroll
        for (int j = 0; j < 4; ++j) acc2[i][j] += t2[i] * b2[j];
    }
#pragma unroll
    for (int i = 0; i < 4; ++i)
#pragma unroll
      for (int j = 0; j < 4; ++j)
        S[(io + ty * 4 + i) * CD + jo + tx * 4 + j] -= acc2[i][j];
  }
}

// ============================================================================
// W = inv(L) by block doubling. Level s: for each pair p (b = 2ps):
//   W[b+s.., b..] = -Wc * Bm * Wa,  Bm stored transposed in S's upper mirror.
// winv_tn: T[p] = Bmt^T * Wa ; winv_nn: W21 = -Wc * T[p].
// ============================================================================
__global__ __launch_bounds__(256) void winv_tn(
    const float* __restrict__ S, const float* __restrict__ W, float* __restrict__ T, int s)
{
  __shared__ float Ua[16][68];
  __shared__ float Wa[16][68];
  const int tid = threadIdx.x, tx = tid & 15, ty = tid >> 4;
  const int p = blockIdx.z, b = 2 * p * s;
  const int i0 = blockIdx.y * 64, j0 = blockIdx.x * 64;
  const int sr = tid >> 4, sc = (tid & 15) * 4;
  float acc[4][4];
#pragma unroll
  for (int i = 0; i < 4; ++i)
#pragma unroll
    for (int j = 0; j < 4; ++j) acc[i][j] = 0.f;

  for (int k0 = 0; k0 < s; k0 += 16) {
    __syncthreads();
    {
      float4 u = *(const float4*)(S + (long)(b + k0 + sr) * CD + (b + s) + i0 + sc);
      *(float4*)&Ua[sr][sc] = u;
      float4 w = *(const float4*)(W + (long)(b + k0 + sr) * 2048 + b + j0 + sc);
      *(float4*)&Wa[sr][sc] = w;
    }
    __syncthreads();
#pragma unroll
    for (int kk = 0; kk < 16; ++kk) {
      float a[4], w2[4];
#pragma unroll
      for (int q = 0; q < 4; ++q) { a[q] = Ua[kk][ty * 4 + q]; w2[q] = Wa[kk][tx * 4 + q]; }
#pragma unroll
      for (int i = 0; i < 4; ++i)
#pragma unroll
        for (int j = 0; j < 4; ++j) acc[i][j] += a[i] * w2[j];
    }
  }
  float* Tp = T + (long)p * s * s;
#pragma unroll
  for (int i = 0; i < 4; ++i)
#pragma unroll
    for (int j = 0; j < 4; ++j)
      Tp[(long)(i0 + ty * 4 + i) * s + j0 + tx * 4 + j] = acc[i][j];
}

__global__ __launch_bounds__(256) void winv_nn(
    float* __restrict__ W, const float* __restrict__ T, int s)
{
  __shared__ float Wc[64][20];
  __shared__ float Tt[16][68];
  const int tid = threadIdx.x, tx = tid & 15, ty = tid >> 4;
  const int p = blockIdx.z, b = 2 * p * s, bs = b + s;
  const int i0 = blockIdx.y * 64, j0 = blockIdx.x * 64;
  const float* Tp = T + (long)p * s * s;
  float acc[4][4];
#pragma unroll
  for (int i = 0; i < 4; ++i)
#pragma unroll
    for (int j = 0; j < 4; ++j) acc[i][j] = 0.f;

  for (int k0 = 0; k0 < s; k0 += 16) {
    __syncthreads();
    {
      const int wr = tid >> 2, wc = (tid & 3) * 4;
      float4 a = *(const float4*)(W + (long)(bs + i0 + wr) * 2048 + bs + k0 + wc);
      *(float4*)&Wc[wr][wc] = a;
      const int tr = tid >> 4, tc = (tid & 15) * 4;
      float4 t2 = *(const float4*)(Tp + (long)(k0 + tr) * s + j0 + tc);
      *(float4*)&Tt[tr][tc] = t2;
    }
    __syncthreads();
#pragma unroll
    for (int kk = 0; kk < 16; ++kk) {
      float a[4], t3[4];
#pragma unroll
      for (int q = 0; q < 4; ++q) { a[q] = Wc[ty * 4 + q][kk]; t3[q] = Tt[kk][tx * 4 + q]; }
#pragma unroll
      for (int i = 0; i < 4; ++i)
#pragma unroll
        for (int j = 0; j < 4; ++j) acc[i][j] += a[i] * t3[j];
    }
  }
#pragma unroll
  for (int i = 0; i < 4; ++i)
#pragma unroll
    for (int j = 0; j < 4; ++j)
      W[(long)(bs + i0 + ty * 4 + i) * 2048 + b + j0 + tx * 4 + j] = -acc[i][j];
}

// ============================================================================
// Host launch.
// ws (80.1 MB): vec 128K | R1: SYM fp32 16M | R2 32M: Cp (16M atomic fp32) /
//   SYMh transient, then W fp32 @+1M, W_f16 @+17M, T @+25M, KinvA @+29M (512K)
//   | R3: BIG f16 32M.
// d_out: Mt_h [0:32M), slotB [32M:64M) -> Xtr [0:32M) -> final Q fp32 (64M).
// ============================================================================
extern "C" void kernel_launch(void* const* d_in, const int* in_sizes, int n_in,
                              void* d_out, int out_size, void* d_ws, size_t ws_size,
                              hipStream_t stream)
{
  const float* s_in  = (const float*)d_in[0];
  const float* sgrad = (const float*)d_in[1];
  const float* L_h0  = (const float*)d_in[2];
  const float* L_c0  = (const float*)d_in[3];
  const float* R_h0  = (const float*)d_in[4];
  const float* R_c0  = (const float*)d_in[5];
  const float* L_bef = (const float*)d_in[6];
  const float* R_bef = (const float*)d_in[7];
  const float* Wih0  = (const float*)d_in[8];
  const float* Whh0  = (const float*)d_in[9];
  const float* bih0  = (const float*)d_in[10];
  const float* bhh0  = (const float*)d_in[11];
  const float* Wih1  = (const float*)d_in[12];
  const float* Whh1  = (const float*)d_in[13];
  const float* bih1  = (const float*)d_in[14];
  const float* bhh1  = (const float*)d_in[15];
  const float* L_W   = (const float*)d_in[16];
  const float* L_b   = (const float*)d_in[17];
  const float* R_W   = (const float*)d_in[18];
  const float* R_b   = (const float*)d_in[19];

  float* out = (float*)d_out;
  char*  ws  = (char*)d_ws;

  const size_t SYM_OFF = (size_t)1 << 17;
  const size_t OVL_OFF = SYM_OFF + ((size_t)16 << 20);
  const size_t BIG_OFF = OVL_OFF + ((size_t)32 << 20);
  float* vec  = (float*)ws;
  float* sums = vec;
  float* ggt  = vec + 4;
  float* gtg  = ggt + RD;
  float* lpre = gtg + CD;
  float* rpre = lpre + RD;
  float*     SYM  = (float*)(ws + SYM_OFF);
  float*     Cp   = (float*)(ws + OVL_OFF);
  _Float16*  SYMh = (_Float16*)(ws + OVL_OFF);
  float*     Wf   = (float*)(ws + OVL_OFF + ((size_t)1 << 20));    // inv(L), 16M
  _Float16*  Wh   = (_Float16*)(ws + OVL_OFF + ((size_t)17 << 20)); // 8M
  float*     Tbuf = (float*)(ws + OVL_OFF + ((size_t)25 << 20));   // 4M
  float*     KinvA= (float*)(ws + OVL_OFF + ((size_t)29 << 20));   // 32 x 16K
  _Float16*  BIG  = (_Float16*)(ws + BIG_OFF);                     // Gt->Pt->Xt->Qh

  _Float16* Mt_h  = (_Float16*)d_out;
  _Float16* slotB = Mt_h + (long)CD * RD;
  _Float16* Xtr   = (_Float16*)d_out;    // overwrites Mt_h (dead by then)

  hipMemsetAsync(vec, 0, (4 + RD) * sizeof(float), stream);
  hipMemsetAsync(Cp, 0, (size_t)CD * CD * sizeof(float), stream);  // gemm #1 atomic acc

  const dim3 blk(256);
  const dim3 blkG(512);
  const dim3 gK8(8, 8, 4);      // M=N=2048 (8x8 256-tiles), K=8192, split-K 4
  const dim3 gK2(32, 8, 1);     // M=2048, N=8192 (8x32 256-tiles), K=2048
  const dim3 gSym(32, 32);
  const int  castBlocks = (CD * RD / 4) / 256;

  cast_f16<<<castBlocks, blk, 0, stream>>>(s_in, Mt_h);
  cast_f16<<<castBlocks, blk, 0, stream>>>(sgrad, slotB);

  // Asym = 0.05 * sym(Mt * Sgt^T)
  gemm_nt_f16<<<gK8, blkG, 0, stream>>>(Mt_h, slotB, Cp, nullptr, nullptr, nullptr,
                                        CD, CD, RD, 4, 0.f, 0.f, 1.f);
  sym_combine<<<gSym, blk, 0, stream>>>(Cp, SYM, CD, 1, 0.05f);
  cast_f16<<<(CD * CD / 4) / 256, blk, 0, stream>>>(SYM, SYMh);

  transpose_cast_f16<<<dim3(RD / 64, CD / 64), blk, 0, stream>>>(s_in, slotB); // Mtr

  // Gt = 0.1*Sgt - Asym*Mt
  gemm_nt_f16<<<gK2, blkG, 0, stream>>>(SYMh, slotB, nullptr, BIG, sgrad, nullptr,
                                        CD, RD, CD, 1, 0.1f, 0.f, -1.f);

  row_sumsq<<<CD, blk, 0, stream>>>(BIG, gtg, 1.f / (float)RD);
  col_sumsq<<<dim3(RD / 256, CD / 256), blk, 0, stream>>>(BIG, ggt);

  lstm_head<<<RD / 256, blk, 0, stream>>>(ggt, RD, L_h0, L_c0, Wih0, Whh0, bih0, bhh0,
                                          Wih1, Whh1, bih1, bhh1, L_W, L_b, lpre, &sums[0]);
  lstm_head<<<CD / 256, blk, 0, stream>>>(gtg, CD, R_h0, R_c0, Wih0, Whh0, bih0, bhh0,
                                          Wih1, Whh1, bih1, bhh1, R_W, R_b, rpre, &sums[1]);

  scale_P<<<(CD * (RD / 4)) / 256, blk, 0, stream>>>(BIG, lpre, rpre, L_bef, R_bef, sums);

  // Bsym = 0.5 * sym(Mt * Pt^T)
  hipMemsetAsync(Cp, 0, (size_t)CD * CD * sizeof(float), stream);
  gemm_nt_f16<<<gK8, blkG, 0, stream>>>(Mt_h, BIG, Cp, nullptr, nullptr, nullptr,
                                        CD, CD, RD, 4, 0.f, 0.f, 1.f);
  sym_combine<<<gSym, blk, 0, stream>>>(Cp, SYM, CD, 1, 0.5f);
  cast_f16<<<(CD * CD / 4) / 256, blk, 0, stream>>>(SYM, SYMh);

  // Xt = Mt - Pt + Bsym*Mt (in place)
  gemm_nt_f16<<<gK2, blkG, 0, stream>>>(SYMh, slotB, nullptr, BIG, s_in, BIG,
                                        CD, RD, CD, 1, 1.f, -1.f, 1.f);

  // Gram S = 0.5 * sym(Xt * Xt^T)
  hipMemsetAsync(Cp, 0, (size_t)CD * CD * sizeof(float), stream);
  gemm_nt_f16<<<gK8, blkG, 0, stream>>>(BIG, BIG, Cp, nullptr, nullptr, nullptr,
                                        CD, CD, RD, 4, 0.f, 0.f, 1.f);
  sym_combine<<<gSym, blk, 0, stream>>>(Cp, SYM, CD, 1, 0.5f);

  hipMemsetAsync(Wf, 0, (size_t)CD * CD * sizeof(float), stream);
  transpose_f16<<<dim3(RD / 64, CD / 64), blk, 0, stream>>>(BIG, Xtr);

  // Cholesky ladder with lookahead fusion: seed potrf(0), then 31 fused
  // dispatches each doing {panel(kb), trail(kb), potrf(kb+1)} concurrently.
  potrf_seed<<<1, blk, 0, stream>>>(SYM, Wf, KinvA);
  for (int kb = 0; kb < 31; ++kb) {
    const int nrem = 31 - kb;
    ptstep_f<<<dim3(nrem, nrem + 2), blk, 0, stream>>>(SYM, Wf, KinvA, kb);
  }

  // W = inv(L) by doubling: 5 levels x 2 dispatches
  for (int lev = 0; lev < 5; ++lev) {
    const int s = 64 << lev, npairs = 16 >> lev;
    const dim3 g(s / 64, s / 64, npairs);
    winv_tn<<<g, blk, 0, stream>>>(SYM, Wf, Tbuf, s);
    winv_nn<<<g, blk, 0, stream>>>(Wf, Tbuf, s);
  }

  // Qh = W * Xt  (NT: A = W_f16 rows, B = Xtr rows), then upcast to d_out
  cast_f16<<<(CD * CD / 4) / 256, blk, 0, stream>>>(Wf, Wh);
  gemm_nt_f16<<<gK2, blkG, 0, stream>>>(Wh, Xtr, nullptr, BIG, nullptr, nullptr,
                                        CD, RD, CD, 1, 0.f, 0.f, 1.f);
  cast_f32<<<(CD * RD / 8) / 256, blk, 0, stream>>>(BIG, out);
}

// Round 7
// 2937.865 us; speedup vs baseline: 1.0948x; 1.0519x over previous
//
#include <hip/hip_runtime.h>
#include <math.h>

#define RD 8192   // r (long dim, contiguous in storage)
#define CD 2048   // c (short dim, rows in storage)

typedef _Float16 f16x8 __attribute__((ext_vector_type(8)));
typedef _Float16 f16x4 __attribute__((ext_vector_type(4)));
typedef float    f32x4 __attribute__((ext_vector_type(4)));

#define GLOBAL_AS __attribute__((address_space(1)))
#define LDS_AS    __attribute__((address_space(3)))

// ============================================================================
// f16 MFMA GEMM (NT): C[i][j] = sum_k A[i*K+k] * B[j*K+k], fp32 accumulate.
// R7 (= R6 design, 2 bugs fixed): 256x256 tile, 8 waves (2Mx4N), BK=64,
// double-buffered, 4-phase interleaved schedule:
//   phase = { ds_read frag subset ; stage half of next tile ; s_barrier ;
//             setprio(1) ; 16 MFMA ; setprio(0) ; s_barrier }
// All next-tile staging issues in phases 0-1; the single vmcnt(0) sits at the
// end of phase 3 (2 full phases after issue -> drain is free).
// LDS chunk-XOR swizzle (chunk ^= row&7): WAVE-UNIFORM LDS dest (m104 —
// global_load_lds takes uniform base + lane*16; per-lane dest was R6's bug),
// swizzle applied on the PER-LANE GLOBAL source (m173 pattern) + matching
// XOR on the ds_read side.
// tri != 0: compute only lower-triangle blocks (bx<=by) — for symmetric C.
// mode A (Cp != 0): split-K partial sums via atomicAdd into zeroed fp32 C.
// mode B (Cp == 0): Of16[i][j] = f16( sgn*acc + beta*Dg[ij] + gamma*Eg[ij] )
// ============================================================================
__global__ __launch_bounds__(512, 2) void gemm_nt_f16(
    const _Float16* __restrict__ A, const _Float16* __restrict__ B,
    float* __restrict__ Cp, _Float16* __restrict__ Of16,
    const float* __restrict__ Dg, const _Float16* __restrict__ Eg,
    int M, int N, int K, int ksplit, int tri, float beta, float gamma, float sgn)
{
  if (tri && blockIdx.x > blockIdx.y) return;

  __shared__ __align__(1024) _Float16 As[2][256 * 64];
  __shared__ __align__(1024) _Float16 Bs[2][256 * 64];
  const int tid = threadIdx.x;
  const int wave = tid >> 6, lane = tid & 63;
  const int wy = wave >> 2, wx = wave & 3;          // 2 x 4 wave grid
  const int bi = blockIdx.y * 256, bj = blockIdx.x * 256;
  const int kchunk = K / ksplit;
  const long k0 = (long)blockIdx.z * kchunk;

  f32x4 acc[8][4];
#pragma unroll
  for (int i = 0; i < 8; ++i)
#pragma unroll
    for (int j = 0; j < 4; ++j) acc[i][j] = (f32x4){0.f, 0.f, 0.f, 0.f};

  const _Float16* aAb = A + (long)bi * K + k0;
  const _Float16* aBb = B + (long)bj * K + k0;
  const int fr = lane & 15;
  const int hi = lane >> 4;

  // Stage one 128x64 half (16 KB) of operand gb into Xs[buf].
  // LDS dest: WAVE-UNIFORM base (h*8192 + q*4096 + wave*512 f16 elems);
  // hardware writes lane l at base + l*16B == ((h*128+row)*64 + cc*8) f16
  // for row=(q*512+tid)>>3, cc=tid&7. The swizzle cs = cc ^ (row&7) lives
  // entirely in the per-lane GLOBAL source address.
#define STAGE_H(gb, Xs, buf, h, kt)                                            \
  {                                                                            \
    _Pragma("unroll")                                                          \
    for (int q = 0; q < 2; ++q) {                                              \
      const int idx = q * 512 + tid;                                           \
      const int row = idx >> 3, cc = idx & 7;                                  \
      const int cs = cc ^ (row & 7);                                           \
      __builtin_amdgcn_global_load_lds(                                        \
          (const GLOBAL_AS unsigned int*)(gb + (long)((h) * 128 + row) * K + (kt) + cs * 8), \
          (LDS_AS unsigned int*)(&Xs[buf][(h) * 8192 + q * 4096 + wave * 512]),\
          16, 0, 0);                                                           \
    }                                                                          \
  }

  // Fragment reads with the matching swizzle on the chunk index.
#define LDA4(mh, kk)                                                           \
  _Pragma("unroll")                                                            \
  for (int j = 0; j < 4; ++j) {                                                \
    const int rA = wy * 128 + ((mh) * 4 + j) * 16 + fr;                        \
    af[j] = *(const f16x8*)(&As[cur][rA * 64 + (((kk) * 4 + hi) ^ (rA & 7)) * 8]); \
  }
#define LDB4(kk)                                                               \
  _Pragma("unroll")                                                            \
  for (int j = 0; j < 4; ++j) {                                                \
    const int rB = wx * 64 + j * 16 + fr;                                      \
    bf[j] = *(const f16x8*)(&Bs[cur][rB * 64 + (((kk) * 4 + hi) ^ (rB & 7)) * 8]); \
  }
#define MFMA16(mh)                                                             \
  _Pragma("unroll")                                                            \
  for (int j = 0; j < 4; ++j)                                                  \
    _Pragma("unroll")                                                          \
    for (int n2 = 0; n2 < 4; ++n2)                                             \
      acc[(mh) * 4 + j][n2] = __builtin_amdgcn_mfma_f32_16x16x32_f16(          \
          af[j], bf[n2], acc[(mh) * 4 + j][n2], 0, 0, 0);

  const int nt_ = kchunk >> 6;        // number of 64-deep K tiles

  // prologue: stage tile 0 fully
  STAGE_H(aAb, As, 0, 0, 0); STAGE_H(aAb, As, 0, 1, 0);
  STAGE_H(aBb, Bs, 0, 0, 0); STAGE_H(aBb, Bs, 0, 1, 0);
  asm volatile("s_waitcnt vmcnt(0)" ::: "memory");
  __syncthreads();

  for (int t = 0; t < nt_; ++t) {
    const int cur = t & 1, nxt = cur ^ 1;
    const int ktn = (t + 1) << 6;
    const bool more = (t + 1 < nt_);
    f16x8 af[4], bf[4];

    // ---- phase 0: kk=0, rows 0-63 of wave tile; stage next A halves ----
    LDB4(0); LDA4(0, 0);
    if (more) { STAGE_H(aAb, As, nxt, 0, ktn); STAGE_H(aAb, As, nxt, 1, ktn); }
    __builtin_amdgcn_s_barrier();
    __builtin_amdgcn_s_setprio(1); MFMA16(0); __builtin_amdgcn_s_setprio(0);
    __builtin_amdgcn_s_barrier();

    // ---- phase 1: kk=0, rows 64-127; stage next B halves ----
    LDA4(1, 0);
    if (more) { STAGE_H(aBb, Bs, nxt, 0, ktn); STAGE_H(aBb, Bs, nxt, 1, ktn); }
    __builtin_amdgcn_s_barrier();
    __builtin_amdgcn_s_setprio(1); MFMA16(1); __builtin_amdgcn_s_setprio(0);
    __builtin_amdgcn_s_barrier();

    // ---- phase 2: kk=1, rows 0-63 ----
    LDB4(1); LDA4(0, 1);
    __builtin_amdgcn_s_barrier();
    __builtin_amdgcn_s_setprio(1); MFMA16(0); __builtin_amdgcn_s_setprio(0);
    __builtin_amdgcn_s_barrier();

    // ---- phase 3: kk=1, rows 64-127; tile-boundary drain (loads are 2
    // full phases old -> wait ~free) ----
    LDA4(1, 1);
    __builtin_amdgcn_s_barrier();
    __builtin_amdgcn_s_setprio(1); MFMA16(1); __builtin_amdgcn_s_setprio(0);
    asm volatile("s_waitcnt vmcnt(0)" ::: "memory");
    __builtin_amdgcn_s_barrier();
  }
#undef STAGE_H
#undef LDA4
#undef LDB4
#undef MFMA16

  const int quad = lane >> 4, fc = lane & 15;
  if (Cp) {
#pragma unroll
    for (int mt = 0; mt < 8; ++mt)
#pragma unroll
      for (int nt = 0; nt < 4; ++nt) {
        const int col = bj + wx * 64 + nt * 16 + fc;
#pragma unroll
        for (int reg = 0; reg < 4; ++reg) {
          const int row = bi + wy * 128 + mt * 16 + quad * 4 + reg;
          atomicAdd(&Cp[(long)row * N + col], acc[mt][nt][reg]);
        }
      }
  } else {
#pragma unroll
    for (int mt = 0; mt < 8; ++mt)
#pragma unroll
      for (int nt = 0; nt < 4; ++nt) {
        const int col = bj + wx * 64 + nt * 16 + fc;
#pragma unroll
        for (int reg = 0; reg < 4; ++reg) {
          const int row = bi + wy * 128 + mt * 16 + quad * 4 + reg;
          const long off = (long)row * N + col;
          float v = sgn * acc[mt][nt][reg];
          if (Dg) v += beta * Dg[off];
          if (Eg) v += gamma * (float)Eg[off];
          Of16[off] = (_Float16)v;
        }
      }
  }
}

// ============================================================================
// sym_combine: out = scale * (C + C^T), n x n. Writes fp32 (outf) and/or
// f16 (outh) — cast fused. outh MUST NOT alias Cp (blocks run concurrently).
// mirror != 0: C was computed lower-triangle-only and is symmetric (Gram)
// -> out(bi,bj) = 2*scale*C_stored (transposed from mirror when bi < bj).
// ============================================================================
__global__ __launch_bounds__(256) void sym_combine(
    const float* __restrict__ Cp, float* __restrict__ outf, _Float16* __restrict__ outh,
    int n, int mirror, float scale)
{
  __shared__ float Ts[64][68];
  const int tid = threadIdx.x;
  const int tx = tid & 15, ty = tid >> 4;
  const int bi = blockIdx.y * 64, bj = blockIdx.x * 64;
  float acc[4][4];
#pragma unroll
  for (int i = 0; i < 4; ++i)
#pragma unroll
    for (int j = 0; j < 4; ++j) acc[i][j] = 0.f;

  if (!mirror) {
#pragma unroll
    for (int i = 0; i < 4; ++i) {
      float4 v = *(const float4*)(Cp + (long)(bi + ty * 4 + i) * n + bj + tx * 4);
      acc[i][0] += v.x; acc[i][1] += v.y; acc[i][2] += v.z; acc[i][3] += v.w;
    }
#pragma unroll
    for (int i = 0; i < 4; ++i) {
      float4 w = *(const float4*)(Cp + (long)(bj + ty * 4 + i) * n + bi + tx * 4);
      *(float4*)&Ts[ty * 4 + i][tx * 4] = w;
    }
    __syncthreads();
#pragma unroll
    for (int i = 0; i < 4; ++i)
#pragma unroll
      for (int j = 0; j < 4; ++j) acc[i][j] += Ts[tx * 4 + j][ty * 4 + i];
  } else if (bi >= bj) {
#pragma unroll
    for (int i = 0; i < 4; ++i) {
      float4 v = *(const float4*)(Cp + (long)(bi + ty * 4 + i) * n + bj + tx * 4);
      acc[i][0] = 2.f * v.x; acc[i][1] = 2.f * v.y; acc[i][2] = 2.f * v.z; acc[i][3] = 2.f * v.w;
    }
  } else {
#pragma unroll
    for (int i = 0; i < 4; ++i) {
      float4 w = *(const float4*)(Cp + (long)(bj + ty * 4 + i) * n + bi + tx * 4);
      *(float4*)&Ts[ty * 4 + i][tx * 4] = w;
    }
    __syncthreads();
#pragma unroll
    for (int i = 0; i < 4; ++i)
#pragma unroll
      for (int j = 0; j < 4; ++j) acc[i][j] = 2.f * Ts[tx * 4 + j][ty * 4 + i];
  }
#pragma unroll
  for (int i = 0; i < 4; ++i) {
    const long off = (long)(bi + ty * 4 + i) * n + bj + tx * 4;
    float4 v; v.x = scale * acc[i][0]; v.y = scale * acc[i][1];
    v.z = scale * acc[i][2]; v.w = scale * acc[i][3];
    if (outf) *(float4*)(outf + off) = v;
    if (outh) {
      f16x4 h; h[0] = (_Float16)v.x; h[1] = (_Float16)v.y;
      h[2] = (_Float16)v.z; h[3] = (_Float16)v.w;
      *(f16x4*)(outh + off) = h;
    }
  }
}

// ============================================================================
// Casts / transposes.
// ============================================================================
__global__ __launch_bounds__(256) void cast_f16(const float* __restrict__ s, _Float16* __restrict__ d)
{
  const long i = ((long)blockIdx.x * 256 + threadIdx.x) * 4;
  float4 v = *(const float4*)(s + i);
  f16x4 o; o[0] = (_Float16)v.x; o[1] = (_Float16)v.y; o[2] = (_Float16)v.z; o[3] = (_Float16)v.w;
  *(f16x4*)(d + i) = o;
}

__global__ __launch_bounds__(256) void cast_f32(const _Float16* __restrict__ s, float* __restrict__ d)
{
  const long i = ((long)blockIdx.x * 256 + threadIdx.x) * 8;
  f16x8 v = *(const f16x8*)(s + i);
  float4 a, b;
  a.x = (float)v[0]; a.y = (float)v[1]; a.z = (float)v[2]; a.w = (float)v[3];
  b.x = (float)v[4]; b.y = (float)v[5]; b.z = (float)v[6]; b.w = (float)v[7];
  *(float4*)(d + i) = a;
  *(float4*)(d + i + 4) = b;
}

__global__ __launch_bounds__(256) void transpose_cast_f16(
    const float* __restrict__ src, _Float16* __restrict__ dst)
{
  __shared__ float T[64][65];
  const int tid = threadIdx.x, tx = tid & 15, ty = tid >> 4;
  const int r0 = blockIdx.x * 64, c0 = blockIdx.y * 64;
#pragma unroll
  for (int i = 0; i < 4; ++i) {
    float4 v = *(const float4*)(src + (long)(c0 + ty * 4 + i) * RD + r0 + tx * 4);
    T[ty * 4 + i][tx * 4 + 0] = v.x; T[ty * 4 + i][tx * 4 + 1] = v.y;
    T[ty * 4 + i][tx * 4 + 2] = v.z; T[ty * 4 + i][tx * 4 + 3] = v.w;
  }
  __syncthreads();
#pragma unroll
  for (int i = 0; i < 4; ++i) {
    f16x4 o;
#pragma unroll
    for (int j = 0; j < 4; ++j) o[j] = (_Float16)T[tx * 4 + j][ty * 4 + i];
    *(f16x4*)(dst + (long)(r0 + ty * 4 + i) * CD + c0 + tx * 4) = o;
  }
}

// f16 (CD x RD) -> f16 (RD x CD) transpose, 64x64 tiles
__global__ __launch_bounds__(256) void transpose_f16(
    const _Float16* __restrict__ src, _Float16* __restrict__ dst)
{
  __shared__ _Float16 T[64][72];
  const int tid = threadIdx.x;
  const int r0 = blockIdx.y * 64;   // src row (CD)
  const int c0 = blockIdx.x * 64;   // src col (RD)
  const int sr = tid >> 2, sc = (tid & 3) * 16;
  {
    f16x8 a = *(const f16x8*)(src + (long)(r0 + sr) * RD + c0 + sc);
    f16x8 b = *(const f16x8*)(src + (long)(r0 + sr) * RD + c0 + sc + 8);
    *(f16x8*)&T[sr][sc] = a;
    *(f16x8*)&T[sr][sc + 8] = b;
  }
  __syncthreads();
  {
    f16x8 a, b;
#pragma unroll
    for (int q = 0; q < 8; ++q) { a[q] = T[sc + q][sr]; b[q] = T[sc + 8 + q][sr]; }
    *(f16x8*)(dst + (long)(c0 + sr) * CD + r0 + sc) = a;
    *(f16x8*)(dst + (long)(c0 + sr) * CD + r0 + sc + 8) = b;
  }
}

// ============================================================================
// Diag-of-Gram reductions on f16 G.
// ============================================================================
__global__ __launch_bounds__(256) void row_sumsq(const _Float16* __restrict__ G, float* __restrict__ out, float inv)
{
  __shared__ float red[256];
  const int tid = threadIdx.x;
  const _Float16* row = G + (long)blockIdx.x * RD;
  float s = 0.f;
  for (int c = tid * 8; c < RD; c += 2048) {
    f16x8 v = *(const f16x8*)(row + c);
#pragma unroll
    for (int u = 0; u < 8; ++u) { float f = (float)v[u]; s += f * f; }
  }
  red[tid] = s; __syncthreads();
  for (int off = 128; off > 0; off >>= 1) { if (tid < off) red[tid] += red[tid + off]; __syncthreads(); }
  if (tid == 0) out[blockIdx.x] = red[0] * inv;
}

__global__ __launch_bounds__(256) void col_sumsq(const _Float16* __restrict__ G, float* __restrict__ out)
{
  const int rr = blockIdx.x * 256 + threadIdx.x;
  const int cc0 = blockIdx.y * 256;
  float s = 0.f;
  for (int i = 0; i < 256; ++i) {
    float v = (float)G[(long)(cc0 + i) * RD + rr];
    s += v * v;
  }
  atomicAdd(&out[rr], s * (1.f / (float)CD));
}

// ============================================================================
// 2-layer LSTM single step + linear head.
// ============================================================================
__device__ __forceinline__ float sigm_(float x) { return 1.f / (1.f + __expf(-x)); }
__device__ __forceinline__ float tanh_(float x) { float e = __expf(2.f * x); return 1.f - 2.f / (e + 1.f); }

__global__ __launch_bounds__(256) void lstm_head(
    const float* __restrict__ diag, int B,
    const float* __restrict__ h0, const float* __restrict__ c0,
    const float* __restrict__ Wih0, const float* __restrict__ Whh0,
    const float* __restrict__ bih0, const float* __restrict__ bhh0,
    const float* __restrict__ Wih1, const float* __restrict__ Whh1,
    const float* __restrict__ bih1, const float* __restrict__ bhh1,
    const float* __restrict__ HW, const float* __restrict__ Hb,
    float* __restrict__ pre, float* __restrict__ sum_out)
{
  __shared__ float w0[80], wh0[1600], b0[80], wi1[1600], wh1[1600], b1[80], hw[20];
  __shared__ float red[256];
  const int tid = threadIdx.x;
  for (int i = tid; i < 80; i += 256) { w0[i] = Wih0[i]; b0[i] = bih0[i] + bhh0[i]; b1[i] = bih1[i] + bhh1[i]; }
  for (int i = tid; i < 1600; i += 256) { wh0[i] = Whh0[i]; wi1[i] = Wih1[i]; wh1[i] = Whh1[i]; }
  if (tid < 20) hw[tid] = HW[tid];
  __syncthreads();

  const int b = blockIdx.x * 256 + tid;
  const float d = diag[b];
  float x = logf(fabsf(d)) * 0.1f;
  x = fminf(fmaxf(x, -1.f), 1.f);

  const float* h0p = h0 + (long)b * 20;
  const float* c0p = c0 + (long)b * 20;
  const float* h1p = h0 + (long)B * 20 + (long)b * 20;
  const float* c1p = c0 + (long)B * 20 + (long)b * 20;

  float h0r[20], hA[20];
#pragma unroll
  for (int m = 0; m < 20; ++m) h0r[m] = h0p[m];
#pragma unroll
  for (int h = 0; h < 20; ++h) {
    float gi = w0[h] * x + b0[h];
    float gf = w0[20 + h] * x + b0[20 + h];
    float gg = w0[40 + h] * x + b0[40 + h];
    float go = w0[60 + h] * x + b0[60 + h];
#pragma unroll
    for (int m = 0; m < 20; ++m) {
      const float hm = h0r[m];
      gi += wh0[h * 20 + m] * hm;
      gf += wh0[(20 + h) * 20 + m] * hm;
      gg += wh0[(40 + h) * 20 + m] * hm;
      go += wh0[(60 + h) * 20 + m] * hm;
    }
    const float cc = sigm_(gf) * c0p[h] + sigm_(gi) * tanh_(gg);
    hA[h] = sigm_(go) * tanh_(cc);
  }
  float h1r[20];
#pragma unroll
  for (int m = 0; m < 20; ++m) h1r[m] = h1p[m];
  float pr = 0.f;
#pragma unroll
  for (int h = 0; h < 20; ++h) {
    float gi = b1[h], gf = b1[20 + h], gg = b1[40 + h], go = b1[60 + h];
#pragma unroll
    for (int m = 0; m < 20; ++m) {
      const float am = hA[m], hm = h1r[m];
      gi += wi1[h * 20 + m] * am + wh1[h * 20 + m] * hm;
      gf += wi1[(20 + h) * 20 + m] * am + wh1[(20 + h) * 20 + m] * hm;
      gg += wi1[(40 + h) * 20 + m] * am + wh1[(40 + h) * 20 + m] * hm;
      go += wi1[(60 + h) * 20 + m] * am + wh1[(60 + h) * 20 + m] * hm;
    }
    const float cc = sigm_(gf) * c1p[h] + sigm_(gi) * tanh_(gg);
    pr += sigm_(go) * tanh_(cc) * hw[h];
  }
  pr = (pr + Hb[0]) * 0.1f;
  pre[b] = pr;

  red[tid] = pr; __syncthreads();
  for (int off = 128; off > 0; off >>= 1) { if (tid < off) red[tid] += red[tid + off]; __syncthreads(); }
  if (tid == 0) atomicAdd(sum_out, red[0]);
}

// ============================================================================
// Pt[cc][rr] = Rv(cc) * Gt[cc][rr] * Lv(rr), in place on f16.
// ============================================================================
__global__ __launch_bounds__(256) void scale_P(
    _Float16* __restrict__ G, const float* __restrict__ lpre, const float* __restrict__ rpre,
    const float* __restrict__ Lbef, const float* __restrict__ Rbef, const float* __restrict__ sums)
{
  const long id4 = ((long)blockIdx.x * 256 + threadIdx.x) * 4;
  const int cc = (int)(id4 >> 13);
  const int rr = (int)(id4 & (RD - 1));
  const float meanl = sums[0] * (1.f / (float)RD);
  const float meanr = sums[1] * (1.f / (float)CD);
  const float rv = fmaxf(rpre[cc] - meanr + 1.f, Rbef[cc]);
  f16x4 g = *(f16x4*)(G + id4);
  float4 lp = *(const float4*)(lpre + rr);
  float4 lb = *(const float4*)(Lbef + rr);
  g[0] = (_Float16)((float)g[0] * rv * fmaxf(lp.x - meanl + 1.f, lb.x));
  g[1] = (_Float16)((float)g[1] * rv * fmaxf(lp.y - meanl + 1.f, lb.y));
  g[2] = (_Float16)((float)g[2] * rv * fmaxf(lp.z - meanl + 1.f, lb.z));
  g[3] = (_Float16)((float)g[3] * rv * fmaxf(lp.w - meanl + 1.f, lb.w));
  *(f16x4*)(G + id4) = g;
}

// ============================================================================
// potrf_block_dev: factor the 64x64 diag block d of S, optionally first
// applying step-kprev's trailing update to it (lookahead fusion).
// Produces: W diag block d  = inv(L_dd)   (full 64x64 incl. upper zeros)
//           KinvA[d]        = inv(L_dd)^T inv(L_dd)
//
// Parallel algorithm (verified R3): deferred-scale right-looking Cholesky
// (64 barriers, rank-1 updates over 256 threads) + inv(L) by in-LDS block
// doubling (4 parallel 16x16 serial inverses, then 16->32, 32->64 matmuls).
// ============================================================================
__device__ __forceinline__ void potrf_block_dev(
    float* __restrict__ S, float* __restrict__ W, float* __restrict__ KinvA,
    int d, int kprev, float (*Ls)[68], float (*Ws)[68], float (*Ts)[68])
{
  const int tid = threadIdx.x;
  const int tx = tid & 15, ty = tid >> 4;
  const long dofs = (long)d * 64;

  for (int t = tid; t < 4096; t += 256) {
    int r = t >> 6, c = t & 63;
    Ls[r][c] = S[(dofs + r) * CD + dofs + c];
  }

  if (kprev >= 0) {
    const float* Kp = KinvA + (long)kprev * 4096;
    const long ko = (long)kprev * 64;
    for (int t = tid; t < 4096; t += 256) {
      int r = t >> 6, c = t & 63;
      Ts[r][c] = S[(dofs + r) * CD + ko + c];   // P = S(d, kprev), pre-step
      Ws[r][c] = Kp[t];                          // Kinv (symmetric)
    }
    __syncthreads();
    float u[4][4];
#pragma unroll
    for (int i = 0; i < 4; ++i)
#pragma unroll
      for (int j = 0; j < 4; ++j) u[i][j] = 0.f;
    for (int m = 0; m < 64; ++m) {
      float a[4], k2[4];
#pragma unroll
      for (int q = 0; q < 4; ++q) { a[q] = Ts[ty * 4 + q][m]; k2[q] = Ws[m][tx * 4 + q]; }
#pragma unroll
      for (int i = 0; i < 4; ++i)
#pragma unroll
        for (int j = 0; j < 4; ++j) u[i][j] += a[i] * k2[j];
    }
    __syncthreads();
#pragma unroll
    for (int i = 0; i < 4; ++i)
#pragma unroll
      for (int j = 0; j < 4; ++j) Ws[ty * 4 + i][tx * 4 + j] = u[i][j];   // U = P*Kinv
    __syncthreads();
    // Ls -= U * P^T   (result stays symmetric)
    float acc[4][4];
#pragma unroll
    for (int i = 0; i < 4; ++i)
#pragma unroll
      for (int j = 0; j < 4; ++j) acc[i][j] = 0.f;
    for (int m = 0; m < 64; ++m) {
      float a[4], b2[4];
#pragma unroll
      for (int q = 0; q < 4; ++q) { a[q] = Ws[ty * 4 + q][m]; b2[q] = Ts[tx * 4 + q][m]; }
#pragma unroll
      for (int i = 0; i < 4; ++i)
#pragma unroll
        for (int j = 0; j < 4; ++j) acc[i][j] += a[i] * b2[j];
    }
#pragma unroll
    for (int i = 0; i < 4; ++i)
#pragma unroll
      for (int j = 0; j < 4; ++j) Ls[ty * 4 + i][tx * 4 + j] -= acc[i][j];
  }

  // --- 1. deferred-scale right-looking Cholesky (lower triangle of Ls) -----
  for (int j = 0; j < 64; ++j) {
    __syncthreads();                                 // step j-1 writes visible
    const float invd = 1.f / Ls[j][j];
    for (int i = j + 1 + ty; i < 64; i += 16) {
      const float vi = Ls[i][j] * invd;
      for (int c = j + 1 + tx; c <= i; c += 16)
        Ls[i][c] -= vi * Ls[c][j];
    }
  }
  __syncthreads();
  if (tid < 64) Ts[0][tid] = 1.f / sqrtf(Ls[tid][tid]);   // rsqrt of pivots
  __syncthreads();
  for (int t = tid; t < 4096; t += 256) {            // scale: L[i][j]=Ls[i][j]*rs[j]
    int r = t >> 6, c = t & 63;
    if (c <= r) Ls[r][c] *= Ts[0][c];
  }
  // zero Ws (upper zeros needed downstream)
  for (int t = tid; t < 4096; t += 256) { int r = t >> 6, c = t & 63; Ws[r][c] = 0.f; }
  __syncthreads();

  // --- 2a. four parallel 16x16 inverses (wave w -> diag block w) -----------
  {
    const int w = tid >> 6, l = tid & 63;
    if (l < 16) {
      const int o = w * 16, c = l;
      float wr[16];
#pragma unroll
      for (int m = 0; m < 16; ++m) {
        float s = 0.f;
#pragma unroll
        for (int k = 0; k < m; ++k) s += Ls[o + m][o + k] * wr[k];
        const float rli = 1.f / Ls[o + m][o + m];
        wr[m] = (m == c) ? rli : -s * rli;
      }
#pragma unroll
      for (int m = 0; m < 16; ++m) Ws[o + m][o + c] = (m < c) ? 0.f : wr[m];
    }
  }
  __syncthreads();

  // --- 2b. doubling 16->32: pairs p=0,1 at b0=32p:
  //     T = L21*W11 (16x16), W21 = -W22*T
  {
    for (int e = tid; e < 512; e += 256) {
      const int p = e >> 8, m = (e >> 4) & 15, c = e & 15, b0 = p * 32;
      float s = 0.f;
#pragma unroll
      for (int k = 0; k < 16; ++k) s += Ls[b0 + 16 + m][b0 + k] * Ws[b0 + k][b0 + c];
      Ts[p * 16 + m][c] = s;
    }
    __syncthreads();
    for (int e = tid; e < 512; e += 256) {
      const int p = e >> 8, m = (e >> 4) & 15, c = e & 15, b0 = p * 32;
      float s = 0.f;
#pragma unroll
      for (int k = 0; k < 16; ++k) s += Ws[b0 + 16 + m][b0 + 16 + k] * Ts[p * 16 + k][c];
      Ws[b0 + 16 + m][b0 + c] = -s;
    }
  }
  __syncthreads();

  // --- 2c. doubling 32->64: T2 = L21'*W11' (32x32), W21' = -W22'*T2 --------
  {
    for (int q = 0; q < 4; ++q) {
      const int e = tid + 256 * q, m = e >> 5, c = e & 31;
      float s = 0.f;
#pragma unroll
      for (int k = 0; k < 32; ++k) s += Ls[32 + m][k] * Ws[k][c];
      Ts[m][c] = s;
    }
    __syncthreads();
    for (int q = 0; q < 4; ++q) {
      const int e = tid + 256 * q, m = e >> 5, c = e & 31;
      float s = 0.f;
#pragma unroll
      for (int k = 0; k < 32; ++k) s += Ws[32 + m][32 + k] * Ts[k][c];
      Ws[32 + m][c] = -s;
    }
  }
  __syncthreads();

  // store W diag block (row-major, incl. upper zeros)
  for (int t = tid; t < 4096; t += 256) {
    int r = t >> 6, c = t & 63;
    W[(dofs + r) * 2048 + dofs + c] = Ws[r][c];
  }
  // KinvA[d] = W^T W : Kinv[a][b] = sum_m Ws[m][a] * Ws[m][b]
  {
    float acc[4][4];
#pragma unroll
    for (int i = 0; i < 4; ++i)
#pragma unroll
      for (int j = 0; j < 4; ++j) acc[i][j] = 0.f;
    for (int m = 0; m < 64; ++m) {
      float a[4], b2[4];
#pragma unroll
      for (int q = 0; q < 4; ++q) { a[q] = Ws[m][ty * 4 + q]; b2[q] = Ws[m][tx * 4 + q]; }
#pragma unroll
      for (int i = 0; i < 4; ++i)
#pragma unroll
        for (int j = 0; j < 4; ++j) acc[i][j] += a[i] * b2[j];
    }
    float* Kd = KinvA + (long)d * 4096;
#pragma unroll
    for (int i = 0; i < 4; ++i)
#pragma unroll
      for (int j = 0; j < 4; ++j)
        Kd[(ty * 4 + i) * 64 + tx * 4 + j] = acc[i][j];
  }
}

__global__ __launch_bounds__(256) void potrf_seed(
    float* __restrict__ S, float* __restrict__ W, float* __restrict__ KinvA)
{
  __shared__ float Ls[64][68];
  __shared__ float Ws[64][68];
  __shared__ float Ts[64][68];
  potrf_block_dev(S, W, KinvA, 0, -1, Ls, Ws, Ts);
}

// ============================================================================
// ptstep_f: fused panel + trailing update + lookahead potrf for step kb.
// by==0 (panel): L(ib,kb) = Spre(ib,kb)*Ws(kb)^T, stored TRANSPOSED in the
//   upper mirror S[kb-rows, ib-cols]. Pre-step reads only.
// 1<=by<=nrem (trail): S(ib,jb) -= Spre(ib,kb)*Kinv[kb]*Spre(jb,kb)^T.
//   Skips (kb+1,kb+1) — the lookahead block handles it.
// by==nrem+1, bx==0 (lookahead): self-update + factor diag kb+1, emit
//   W diag kb+1 and Kinv[kb+1] for the next dispatch.
// All roles read only column-kb pre-values + disjoint outputs -> race-free.
// ============================================================================
__global__ __launch_bounds__(256) void ptstep_f(
    float* __restrict__ S, float* __restrict__ W, float* __restrict__ KinvA, int kb)
{
  __shared__ float As[64][68];
  __shared__ float Bs[64][68];
  __shared__ float Ts[64][68];
  const int tid = threadIdx.x, tx = tid & 15, ty = tid >> 4;
  const long ko = (long)kb * 64;
  const int nrem = 31 - kb;

  if (blockIdx.y == (unsigned)(nrem + 1)) {
    if (blockIdx.x != 0) return;
    potrf_block_dev(S, W, KinvA, kb + 1, kb, As, Bs, Ts);
    return;
  }

  if (blockIdx.y == 0) {
    const int ib = kb + 1 + blockIdx.x;
    const long ro = (long)ib * 64;
    for (int t = tid; t < 4096; t += 256) {
      int r = t >> 6, c = t & 63;
      As[r][c] = S[(ro + r) * CD + ko + c];
      Bs[r][c] = W[(ko + r) * 2048 + ko + c];   // Ws = inv(Lkk)
    }
    __syncthreads();
    float acc[4][4];
#pragma unroll
    for (int i = 0; i < 4; ++i)
#pragma unroll
      for (int j = 0; j < 4; ++j) acc[i][j] = 0.f;
    for (int m = 0; m < 64; ++m) {
      float a[4], w[4];
#pragma unroll
      for (int q = 0; q < 4; ++q) { a[q] = As[ty * 4 + q][m]; w[q] = Bs[tx * 4 + q][m]; }
#pragma unroll
      for (int i = 0; i < 4; ++i)
#pragma unroll
        for (int j = 0; j < 4; ++j) acc[i][j] += a[i] * w[j];
    }
    // store transposed: S[kb-row j][ib-col i] = Lblk[i][j]
#pragma unroll
    for (int i = 0; i < 4; ++i)
#pragma unroll
      for (int j = 0; j < 4; ++j)
        S[(ko + tx * 4 + j) * CD + ro + ty * 4 + i] = acc[i][j];
  } else {
    const int ib = kb + blockIdx.y;            // 1..nrem -> kb+1..31
    const int jb = kb + 1 + blockIdx.x;
    if (jb > ib) return;
    if (blockIdx.y == 1 && blockIdx.x == 0) return;   // (kb+1,kb+1): lookahead's
    const long io = (long)ib * 64, jo = (long)jb * 64;
    const float* Kp = KinvA + (long)kb * 4096;
    for (int t = tid; t < 4096; t += 256) {
      int r = t >> 6, c = t & 63;
      As[r][c] = S[(io + r) * CD + ko + c];
      Bs[r][c] = Kp[t];
    }
    __syncthreads();
    float acc[4][4];
#pragma unroll
    for (int i = 0; i < 4; ++i)
#pragma unroll
      for (int j = 0; j < 4; ++j) acc[i][j] = 0.f;
    for (int m = 0; m < 64; ++m) {
      float a[4], k2[4];
#pragma unroll
      for (int q = 0; q < 4; ++q) { a[q] = As[ty * 4 + q][m]; k2[q] = Bs[m][tx * 4 + q]; }
#pragma unroll
      for (int i = 0; i < 4; ++i)
#pragma unroll
        for (int j = 0; j < 4; ++j) acc[i][j] += a[i] * k2[j];
    }
#pragma unroll
    for (int i = 0; i < 4; ++i)
#pragma unroll
      for (int j = 0; j < 4; ++j) Ts[ty * 4 + i][tx * 4 + j] = acc[i][j];
    __syncthreads();
    for (int t = tid; t < 4096; t += 256) {
      int r = t >> 6, c = t & 63;
      Bs[r][c] = S[(jo + r) * CD + ko + c];
    }
    __syncthreads();
    float acc2[4][4];
#pragma unroll
    for (int i = 0; i < 4; ++i)
#pragma unroll
      for (int j = 0; j < 4; ++j) acc2[i][j] = 0.f;
    for (int m = 0; m < 64; ++m) {
      float t2[4], b2[4];
#pragma unroll
      for (int q = 0; q < 4; ++q) { t2[q] = Ts[ty * 4 + q][m]; b2[q] = Bs[tx * 4 + q][m]; }
#pragma unroll
      for (int i = 0; i < 4; ++i)
#pragma unroll
        for (int j = 0; j < 4; ++j) acc2[i][j] += t2[i] * b2[j];
    }
#pragma unroll
    for (int i = 0; i < 4; ++i)
#pragma unroll
      for (int j = 0; j < 4; ++j)
        S[(io + ty * 4 + i) * CD + jo + tx * 4 + j] -= acc2[i][j];
  }
}

// ============================================================================
// W = inv(L) by block doubling. Level s: for each pair p (b = 2ps):
//   W[b+s.., b..] = -Wc * Bm * Wa,  Bm stored transposed in S's upper mirror.
// winv_tn: T[p] = Bmt^T * Wa ; winv_nn: W21 = -Wc * T[p].
// ============================================================================
__global__ __launch_bounds__(256) void winv_tn(
    const float* __restrict__ S, const float* __restrict__ W, float* __restrict__ T, int s)
{
  __shared__ float Ua[16][68];
  __shared__ float Wa[16][68];
  const int tid = threadIdx.x, tx = tid & 15, ty = tid >> 4;
  const int p = blockIdx.z, b = 2 * p * s;
  const int i0 = blockIdx.y * 64, j0 = blockIdx.x * 64;
  const int sr = tid >> 4, sc = (tid & 15) * 4;
  float acc[4][4];
#pragma unroll
  for (int i = 0; i < 4; ++i)
#pragma unroll
    for (int j = 0; j < 4; ++j) acc[i][j] = 0.f;

  for (int k0 = 0; k0 < s; k0 += 16) {
    __syncthreads();
    {
      float4 u = *(const float4*)(S + (long)(b + k0 + sr) * CD + (b + s) + i0 + sc);
      *(float4*)&Ua[sr][sc] = u;
      float4 w = *(const float4*)(W + (long)(b + k0 + sr) * 2048 + b + j0 + sc);
      *(float4*)&Wa[sr][sc] = w;
    }
    __syncthreads();
#pragma unroll
    for (int kk = 0; kk < 16; ++kk) {
      float a[4], w2[4];
#pragma unroll
      for (int q = 0; q < 4; ++q) { a[q] = Ua[kk][ty * 4 + q]; w2[q] = Wa[kk][tx * 4 + q]; }
#pragma unroll
      for (int i = 0; i < 4; ++i)
#pragma unroll
        for (int j = 0; j < 4; ++j) acc[i][j] += a[i] * w2[j];
    }
  }
  float* Tp = T + (long)p * s * s;
#pragma unroll
  for (int i = 0; i < 4; ++i)
#pragma unroll
    for (int j = 0; j < 4; ++j)
      Tp[(long)(i0 + ty * 4 + i) * s + j0 + tx * 4 + j] = acc[i][j];
}

__global__ __launch_bounds__(256) void winv_nn(
    float* __restrict__ W, const float* __restrict__ T, int s)
{
  __shared__ float Wc[64][20];
  __shared__ float Tt[16][68];
  const int tid = threadIdx.x, tx = tid & 15, ty = tid >> 4;
  const int p = blockIdx.z, b = 2 * p * s, bs = b + s;
  const int i0 = blockIdx.y * 64, j0 = blockIdx.x * 64;
  const float* Tp = T + (long)p * s * s;
  float acc[4][4];
#pragma unroll
  for (int i = 0; i < 4; ++i)
#pragma unroll
    for (int j = 0; j < 4; ++j) acc[i][j] = 0.f;

  for (int k0 = 0; k0 < s; k0 += 16) {
    __syncthreads();
    {
      const int wr = tid >> 2, wc = (tid & 3) * 4;
      float4 a = *(const float4*)(W + (long)(bs + i0 + wr) * 2048 + bs + k0 + wc);
      *(float4*)&Wc[wr][wc] = a;
      const int tr = tid >> 4, tc = (tid & 15) * 4;
      float4 t2 = *(const float4*)(Tp + (long)(k0 + tr) * s + j0 + tc);
      *(float4*)&Tt[tr][tc] = t2;
    }
    __syncthreads();
#pragma unroll
    for (int kk = 0; kk < 16; ++kk) {
      float a[4], t3[4];
#pragma unroll
      for (int q = 0; q < 4; ++q) { a[q] = Wc[ty * 4 + q][kk]; t3[q] = Tt[kk][tx * 4 + q]; }
#pragma unroll
      for (int i = 0; i < 4; ++i)
#pragma unroll
        for (int j = 0; j < 4; ++j) acc[i][j] += a[i] * t3[j];
    }
  }
#pragma unroll
  for (int i = 0; i < 4; ++i)
#pragma unroll
    for (int j = 0; j < 4; ++j)
      W[(long)(bs + i0 + ty * 4 + i) * 2048 + b + j0 + tx * 4 + j] = -acc[i][j];
}

// ============================================================================
// Host launch.
// ws (80.1 MB): vec 128K | R1 @SYM_OFF (16M): SYMh f16 (Asym/Bsym, 8M) then
//   SYM fp32 (Gram->ladder) — disjoint in TIME, never aliased with Cp |
//   R2 @OVL_OFF (32M): Cp (16M atomic fp32) transient, then W fp32 @+1M,
//   W_f16 @+17M, T @+25M, KinvA @+29M (512K) | R3: BIG f16 32M.
// d_out: Mt_h [0:32M), slotB [32M:64M) -> Xtr [0:32M) -> final Q fp32 (64M).
// ============================================================================
extern "C" void kernel_launch(void* const* d_in, const int* in_sizes, int n_in,
                              void* d_out, int out_size, void* d_ws, size_t ws_size,
                              hipStream_t stream)
{
  const float* s_in  = (const float*)d_in[0];
  const float* sgrad = (const float*)d_in[1];
  const float* L_h0  = (const float*)d_in[2];
  const float* L_c0  = (const float*)d_in[3];
  const float* R_h0  = (const float*)d_in[4];
  const float* R_c0  = (const float*)d_in[5];
  const float* L_bef = (const float*)d_in[6];
  const float* R_bef = (const float*)d_in[7];
  const float* Wih0  = (const float*)d_in[8];
  const float* Whh0  = (const float*)d_in[9];
  const float* bih0  = (const float*)d_in[10];
  const float* bhh0  = (const float*)d_in[11];
  const float* Wih1  = (const float*)d_in[12];
  const float* Whh1  = (const float*)d_in[13];
  const float* bih1  = (const float*)d_in[14];
  const float* bhh1  = (const float*)d_in[15];
  const float* L_W   = (const float*)d_in[16];
  const float* L_b   = (const float*)d_in[17];
  const float* R_W   = (const float*)d_in[18];
  const float* R_b   = (const float*)d_in[19];

  float* out = (float*)d_out;
  char*  ws  = (char*)d_ws;

  const size_t SYM_OFF = (size_t)1 << 17;
  const size_t OVL_OFF = SYM_OFF + ((size_t)16 << 20);
  const size_t BIG_OFF = OVL_OFF + ((size_t)32 << 20);
  float* vec  = (float*)ws;
  float* sums = vec;
  float* ggt  = vec + 4;
  float* gtg  = ggt + RD;
  float* lpre = gtg + CD;
  float* rpre = lpre + RD;
  float*     SYM  = (float*)(ws + SYM_OFF);          // fp32, Gram -> ladder
  _Float16*  SYMh = (_Float16*)(ws + SYM_OFF);       // f16 Asym/Bsym (disjoint in time from SYM fp32 use; NEVER aliases Cp)
  float*     Cp   = (float*)(ws + OVL_OFF);
  float*     Wf   = (float*)(ws + OVL_OFF + ((size_t)1 << 20));    // inv(L), 16M
  _Float16*  Wh   = (_Float16*)(ws + OVL_OFF + ((size_t)17 << 20)); // 8M
  float*     Tbuf = (float*)(ws + OVL_OFF + ((size_t)25 << 20));   // 4M
  float*     KinvA= (float*)(ws + OVL_OFF + ((size_t)29 << 20));   // 32 x 16K
  _Float16*  BIG  = (_Float16*)(ws + BIG_OFF);                     // Gt->Pt->Xt->Qh

  _Float16* Mt_h  = (_Float16*)d_out;
  _Float16* slotB = Mt_h + (long)CD * RD;
  _Float16* Xtr   = (_Float16*)d_out;    // overwrites Mt_h (dead by then)

  hipMemsetAsync(vec, 0, (4 + RD) * sizeof(float), stream);
  hipMemsetAsync(Cp, 0, (size_t)CD * CD * sizeof(float), stream);  // gemm #1 atomic acc

  const dim3 blk(256);
  const dim3 blkG(512);
  const dim3 gK8(8, 8, 4);      // M=N=2048 (8x8 256-tiles), K=8192, split-K 4
  const dim3 gK2(32, 8, 1);     // M=2048, N=8192 (8x32 256-tiles), K=2048
  const dim3 gSym(32, 32);
  const int  castBlocks = (CD * RD / 4) / 256;

  cast_f16<<<castBlocks, blk, 0, stream>>>(s_in, Mt_h);
  cast_f16<<<castBlocks, blk, 0, stream>>>(sgrad, slotB);

  // Asym = 0.05 * sym(Mt * Sgt^T)  (sym_combine writes f16 to SYMh @SYM_OFF)
  gemm_nt_f16<<<gK8, blkG, 0, stream>>>(Mt_h, slotB, Cp, nullptr, nullptr, nullptr,
                                        CD, CD, RD, 4, 0, 0.f, 0.f, 1.f);
  sym_combine<<<gSym, blk, 0, stream>>>(Cp, nullptr, SYMh, CD, 0, 0.05f);

  transpose_cast_f16<<<dim3(RD / 64, CD / 64), blk, 0, stream>>>(s_in, slotB); // Mtr

  // Gt = 0.1*Sgt - Asym*Mt
  gemm_nt_f16<<<gK2, blkG, 0, stream>>>(SYMh, slotB, nullptr, BIG, sgrad, nullptr,
                                        CD, RD, CD, 1, 0, 0.1f, 0.f, -1.f);

  row_sumsq<<<CD, blk, 0, stream>>>(BIG, gtg, 1.f / (float)RD);
  col_sumsq<<<dim3(RD / 256, CD / 256), blk, 0, stream>>>(BIG, ggt);

  lstm_head<<<RD / 256, blk, 0, stream>>>(ggt, RD, L_h0, L_c0, Wih0, Whh0, bih0, bhh0,
                                          Wih1, Whh1, bih1, bhh1, L_W, L_b, lpre, &sums[0]);
  lstm_head<<<CD / 256, blk, 0, stream>>>(gtg, CD, R_h0, R_c0, Wih0, Whh0, bih0, bhh0,
                                          Wih1, Whh1, bih1, bhh1, R_W, R_b, rpre, &sums[1]);

  scale_P<<<(CD * (RD / 4)) / 256, blk, 0, stream>>>(BIG, lpre, rpre, L_bef, R_bef, sums);

  // Bsym = 0.5 * sym(Mt * Pt^T)
  hipMemsetAsync(Cp, 0, (size_t)CD * CD * sizeof(float), stream);
  gemm_nt_f16<<<gK8, blkG, 0, stream>>>(Mt_h, BIG, Cp, nullptr, nullptr, nullptr,
                                        CD, CD, RD, 4, 0, 0.f, 0.f, 1.f);
  sym_combine<<<gSym, blk, 0, stream>>>(Cp, nullptr, SYMh, CD, 0, 0.5f);

  // Xt = Mt - Pt + Bsym*Mt (in place)
  gemm_nt_f16<<<gK2, blkG, 0, stream>>>(SYMh, slotB, nullptr, BIG, s_in, BIG,
                                        CD, RD, CD, 1, 0, 1.f, -1.f, 1.f);

  // Gram S = 0.5 * sym(Xt * Xt^T): symmetric product -> lower-triangle blocks
  // only (tri=1), mirrored in sym_combine (writes SYM fp32; SYMh dead now).
  hipMemsetAsync(Cp, 0, (size_t)CD * CD * sizeof(float), stream);
  gemm_nt_f16<<<gK8, blkG, 0, stream>>>(BIG, BIG, Cp, nullptr, nullptr, nullptr,
                                        CD, CD, RD, 4, 1, 0.f, 0.f, 1.f);
  sym_combine<<<gSym, blk, 0, stream>>>(Cp, SYM, nullptr, CD, 1, 0.5f);

  hipMemsetAsync(Wf, 0, (size_t)CD * CD * sizeof(float), stream);
  transpose_f16<<<dim3(RD / 64, CD / 64), blk, 0, stream>>>(BIG, Xtr);

  // Cholesky ladder with lookahead fusion: seed potrf(0), then 31 fused
  // dispatches each doing {panel(kb), trail(kb), potrf(kb+1)} concurrently.
  potrf_seed<<<1, blk, 0, stream>>>(SYM, Wf, KinvA);
  for (int kb = 0; kb < 31; ++kb) {
    const int nrem = 31 - kb;
    ptstep_f<<<dim3(nrem, nrem + 2), blk, 0, stream>>>(SYM, Wf, KinvA, kb);
  }

  // W = inv(L) by doubling: 5 levels x 2 dispatches
  for (int lev = 0; lev < 5; ++lev) {
    const int s = 64 << lev, npairs = 16 >> lev;
    const dim3 g(s / 64, s / 64, npairs);
    winv_tn<<<g, blk, 0, stream>>>(SYM, Wf, Tbuf, s);
    winv_nn<<<g, blk, 0, stream>>>(Wf, Tbuf, s);
  }

  // Qh = W * Xt  (NT: A = W_f16 rows, B = Xtr rows), then upcast to d_out
  cast_f16<<<(CD * CD / 4) / 256, blk, 0, stream>>>(Wf, Wh);
  gemm_nt_f16<<<gK2, blkG, 0, stream>>>(Wh, Xtr, nullptr, BIG, nullptr, nullptr,
                                        CD, RD, CD, 1, 0, 0.f, 0.f, 1.f);
  cast_f32<<<(CD * RD / 8) / 256, blk, 0, stream>>>(BIG, out);
}